// Round 1
// baseline (703.506 us; speedup 1.0000x reference)
//
#include <hip/hip_runtime.h>

// GCN 2-layer encoder: N=50000 nodes, E=800000 edges, 256 -> 128 -> 64.
// fp32 throughout (threshold 1e-2 absolute; fp32 gives ~1e-5).

#define IN_C 256
#define HID 128
#define OUTC 64

// ---- edge index access (int64 vs int32 detected at runtime) ----------------
__device__ __forceinline__ int edge_at(const void* ei, long long idx, int is32) {
    return is32 ? ((const int*)ei)[idx] : (int)((const long long*)ei)[idx];
}

__global__ void detect_kernel(const unsigned long long* ei, int* flag) {
    if (threadIdx.x == 0 && blockIdx.x == 0) {
        int is32 = 0;
        for (int i = 0; i < 64; ++i)
            if (ei[i] >> 32) { is32 = 1; break; }
        *flag = is32;  // 1 => data is int32 pairs, 0 => true int64
    }
}

// ---- degree over dst (self-loop added later as +1) --------------------------
__global__ void deg_kernel(const void* ei, const int* __restrict__ flag,
                           float* __restrict__ deg, int E) {
    int is32 = *flag;
    long long stride = (long long)gridDim.x * blockDim.x;
    for (long long e = (long long)blockIdx.x * blockDim.x + threadIdx.x; e < E; e += stride) {
        int d = edge_at(ei, (long long)E + e, is32);
        unsafeAtomicAdd(&deg[d], 1.0f);
    }
}

__global__ void dis_kernel(float* deg, int N) {
    int n = blockIdx.x * blockDim.x + threadIdx.x;
    if (n < N) deg[n] = rsqrtf(deg[n] + 1.0f);  // +1 = self loop; deg>0 always
}

// ---- GEMM1: H[N,128] = X[N,256] @ W1[256,128] ------------------------------
__global__ __launch_bounds__(256) void gemm1_kernel(const float* __restrict__ X,
                                                    const float* __restrict__ W,
                                                    float* __restrict__ H, int N) {
    __shared__ float xs[64][68];    // 64 rows x 64 k, padded (stride 272B, 16B-aligned)
    __shared__ float ws[64][128];   // 64 k x 128 cols
    int tid = threadIdx.x;
    long long row0 = (long long)blockIdx.x * 64;
    int r0 = (tid >> 5) * 8;        // 8 row-groups of 8
    int c0 = (tid & 31) * 4;        // 32 col-groups of 4
    float acc[8][4] = {};
    for (int k0 = 0; k0 < IN_C; k0 += 64) {
        __syncthreads();
        {   // stage X tile
            int col4 = (tid & 15) * 4;
            for (int rr = tid >> 4; rr < 64; rr += 16) {
                long long gr = row0 + rr;
                float4 v = make_float4(0.f, 0.f, 0.f, 0.f);
                if (gr < N) v = *(const float4*)&X[gr * IN_C + k0 + col4];
                *(float4*)&xs[rr][col4] = v;
            }
        }
        {   // stage W tile
            int col4 = (tid & 31) * 4;
            for (int rr = tid >> 5; rr < 64; rr += 8)
                *(float4*)&ws[rr][col4] = *(const float4*)&W[(long long)(k0 + rr) * HID + col4];
        }
        __syncthreads();
        #pragma unroll 8
        for (int k = 0; k < 64; ++k) {
            float4 wb = *(const float4*)&ws[k][c0];
            #pragma unroll
            for (int i = 0; i < 8; ++i) {
                float xa = xs[r0 + i][k];
                acc[i][0] += xa * wb.x; acc[i][1] += xa * wb.y;
                acc[i][2] += xa * wb.z; acc[i][3] += xa * wb.w;
            }
        }
    }
    for (int i = 0; i < 8; ++i) {
        long long gr = row0 + r0 + i;
        if (gr < N)
            *(float4*)&H[gr * HID + c0] =
                make_float4(acc[i][0], acc[i][1], acc[i][2], acc[i][3]);
    }
}

// ---- GEMM2: H2[N,64] = relu(A[N,128] + b1) @ W2[128,64] --------------------
__global__ __launch_bounds__(256) void gemm2_kernel(const float* __restrict__ A,
                                                    const float* __restrict__ b1,
                                                    const float* __restrict__ W,
                                                    float* __restrict__ H, int N) {
    __shared__ float xs[64][68];
    __shared__ float ws[64][64];
    int tid = threadIdx.x;
    long long row0 = (long long)blockIdx.x * 64;
    int r0 = (tid >> 4) * 4;        // 16 row-groups of 4
    int c0 = (tid & 15) * 4;        // 16 col-groups of 4
    float acc[4][4] = {};
    for (int k0 = 0; k0 < HID; k0 += 64) {
        __syncthreads();
        {   // stage A tile with fused +b1, relu
            int col4 = (tid & 15) * 4;
            float4 bb = *(const float4*)&b1[k0 + col4];
            for (int rr = tid >> 4; rr < 64; rr += 16) {
                long long gr = row0 + rr;
                float4 v = make_float4(0.f, 0.f, 0.f, 0.f);
                if (gr < N) {
                    v = *(const float4*)&A[gr * HID + k0 + col4];
                    v.x = fmaxf(v.x + bb.x, 0.f); v.y = fmaxf(v.y + bb.y, 0.f);
                    v.z = fmaxf(v.z + bb.z, 0.f); v.w = fmaxf(v.w + bb.w, 0.f);
                }
                *(float4*)&xs[rr][col4] = v;
            }
        }
        {   // stage W2 tile
            int col4 = (tid & 15) * 4;
            for (int rr = tid >> 4; rr < 64; rr += 16)
                *(float4*)&ws[rr][col4] = *(const float4*)&W[(long long)(k0 + rr) * OUTC + col4];
        }
        __syncthreads();
        #pragma unroll 8
        for (int k = 0; k < 64; ++k) {
            float4 wb = *(const float4*)&ws[k][c0];
            #pragma unroll
            for (int i = 0; i < 4; ++i) {
                float xa = xs[r0 + i][k];
                acc[i][0] += xa * wb.x; acc[i][1] += xa * wb.y;
                acc[i][2] += xa * wb.z; acc[i][3] += xa * wb.w;
            }
        }
    }
    for (int i = 0; i < 4; ++i) {
        long long gr = row0 + r0 + i;
        if (gr < N)
            *(float4*)&H[gr * OUTC + c0] =
                make_float4(acc[i][0], acc[i][1], acc[i][2], acc[i][3]);
    }
}

// ---- edge aggregation: agg[dst] += h[src] * dis[src]*dis[dst] --------------
// One wave (64 lanes) per edge; self-loops appended as e in [E, E+N).
template <int F>
__global__ void edge_agg_kernel(const float* __restrict__ Hin,
                                const float* __restrict__ dis,
                                const void* ei, const int* __restrict__ flag,
                                float* __restrict__ agg, int E, int N) {
    int is32 = *flag;
    long long wid = ((long long)blockIdx.x * blockDim.x + threadIdx.x) >> 6;
    int lane = threadIdx.x & 63;
    long long nw = ((long long)gridDim.x * blockDim.x) >> 6;
    long long total = (long long)E + N;
    for (long long e = wid; e < total; e += nw) {
        int s, d; float nrm;
        if (e < E) {
            s = edge_at(ei, e, is32);
            d = edge_at(ei, (long long)E + e, is32);
            nrm = dis[s] * dis[d];
        } else {
            s = d = (int)(e - E);
            nrm = dis[s] * dis[s];
        }
        const float* hr = &Hin[(long long)s * F];
        float* ar = &agg[(long long)d * F];
        #pragma unroll
        for (int c = lane; c < F; c += 64)
            unsafeAtomicAdd(&ar[c], hr[c] * nrm);
    }
}

// ---- init output with bias b2 ----------------------------------------------
__global__ void init_out_kernel(float* __restrict__ out, const float* __restrict__ b2,
                                long long total) {
    long long stride = (long long)gridDim.x * blockDim.x;
    for (long long i = (long long)blockIdx.x * blockDim.x + threadIdx.x; i < total; i += stride)
        out[i] = b2[i & (OUTC - 1)];
}

extern "C" void kernel_launch(void* const* d_in, const int* in_sizes, int n_in,
                              void* d_out, int out_size, void* d_ws, size_t ws_size,
                              hipStream_t stream) {
    const float* x  = (const float*)d_in[0];
    const void*  ei = d_in[1];
    const float* W1 = (const float*)d_in[2];
    const float* b1 = (const float*)d_in[3];
    const float* W2 = (const float*)d_in[4];
    const float* b2 = (const float*)d_in[5];
    float* out = (float*)d_out;
    int N = in_sizes[0] / IN_C;    // 50000
    int E = in_sizes[1] / 2;       // 800000 (element count is dtype-independent)

    char* ws = (char*)d_ws;
    int*   flag = (int*)ws;
    float* dis  = (float*)(ws + 256);
    size_t off  = 256 + (((size_t)N * 4 + 255) / 256) * 256;
    float* H1   = (float*)(ws + off); off += (size_t)N * HID * 4;
    float* AG1  = (float*)(ws + off); off += (size_t)N * HID * 4;
    float* H2   = (float*)(ws + off); off += (size_t)N * OUTC * 4;

    hipMemsetAsync(dis, 0, (size_t)N * 4, stream);
    hipMemsetAsync(AG1, 0, (size_t)N * HID * 4, stream);

    detect_kernel<<<1, 64, 0, stream>>>((const unsigned long long*)ei, flag);
    deg_kernel<<<1024, 256, 0, stream>>>(ei, flag, dis, E);
    dis_kernel<<<(N + 255) / 256, 256, 0, stream>>>(dis, N);
    gemm1_kernel<<<(N + 63) / 64, 256, 0, stream>>>(x, W1, H1, N);
    edge_agg_kernel<HID><<<4096, 256, 0, stream>>>(H1, dis, ei, flag, AG1, E, N);
    gemm2_kernel<<<(N + 63) / 64, 256, 0, stream>>>(AG1, b1, W2, H2, N);
    init_out_kernel<<<2048, 256, 0, stream>>>(out, b2, (long long)N * OUTC);
    edge_agg_kernel<OUTC><<<4096, 256, 0, stream>>>(H2, dis, ei, flag, out, E, N);
}

// Round 2
// 457.068 us; speedup vs baseline: 1.5392x; 1.5392x over previous
//
#include <hip/hip_runtime.h>

// GCN 2-layer encoder: N=50000 nodes, E=800000 edges, 256 -> 128 -> 64.
// fp32 throughout. Round 2: CSR counting-sort by dst, atomic-free aggregation.

#define IN_C 256
#define HID 128
#define OUTC 64

// ---- edge index access (int64 vs int32 detected at runtime) ----------------
__device__ __forceinline__ int edge_at(const void* ei, long long idx, int is32) {
    return is32 ? ((const int*)ei)[idx] : (int)((const long long*)ei)[idx];
}

__global__ void detect_kernel(const unsigned long long* ei, int* flag) {
    if (threadIdx.x == 0 && blockIdx.x == 0) {
        int is32 = 0;
        for (int i = 0; i < 64; ++i)
            if (ei[i] >> 32) { is32 = 1; break; }
        *flag = is32;  // 1 => data is int32 pairs, 0 => true int64
    }
}

// ---- integer degree histogram over dst -------------------------------------
__global__ void degi_kernel(const void* ei, const int* __restrict__ flag,
                            int* __restrict__ degi, int E) {
    int is32 = *flag;
    long long stride = (long long)gridDim.x * blockDim.x;
    for (long long e = (long long)blockIdx.x * blockDim.x + threadIdx.x; e < E; e += stride) {
        int d = edge_at(ei, (long long)E + e, is32);
        atomicAdd(&degi[d], 1);
    }
}

__global__ void dis_kernel(const int* __restrict__ degi, float* __restrict__ dis, int N) {
    int n = blockIdx.x * blockDim.x + threadIdx.x;
    if (n < N) dis[n] = rsqrtf((float)degi[n] + 1.0f);  // +1 = self loop
}

// ---- single-block exclusive scan over N (=50000) ---------------------------
__global__ __launch_bounds__(1024) void scan_kernel(const int* __restrict__ degi,
                                                    int* __restrict__ row_ptr,
                                                    int* __restrict__ cursor, int N) {
    __shared__ int part[1024];
    int t = threadIdx.x;
    int ch = (N + 1023) / 1024;
    int lo = t * ch, hi = min(lo + ch, N);
    int s = 0;
    for (int i = lo; i < hi; ++i) s += degi[i];
    part[t] = s;
    __syncthreads();
    if (t == 0) {
        int run = 0;
        for (int i = 0; i < 1024; ++i) { int v = part[i]; part[i] = run; run += v; }
    }
    __syncthreads();
    int base = part[t];
    for (int i = lo; i < hi; ++i) { row_ptr[i] = base; cursor[i] = base; base += degi[i]; }
    if (lo < N && hi == N) row_ptr[N] = base;  // total = E
}

// ---- scatter src ids into dst-sorted order ---------------------------------
__global__ void scatter_kernel(const void* ei, const int* __restrict__ flag,
                               int* __restrict__ cursor, int* __restrict__ sorted_src,
                               int E) {
    int is32 = *flag;
    long long stride = (long long)gridDim.x * blockDim.x;
    for (long long e = (long long)blockIdx.x * blockDim.x + threadIdx.x; e < E; e += stride) {
        int s = edge_at(ei, e, is32);
        int d = edge_at(ei, (long long)E + e, is32);
        int pos = atomicAdd(&cursor[d], 1);
        sorted_src[pos] = s;
    }
}

// ---- GEMM1: H[N,128] = X[N,256] @ W1[256,128] ------------------------------
__global__ __launch_bounds__(256) void gemm1_kernel(const float* __restrict__ X,
                                                    const float* __restrict__ W,
                                                    float* __restrict__ H, int N) {
    __shared__ float xs[64][68];
    __shared__ float ws[64][128];
    int tid = threadIdx.x;
    long long row0 = (long long)blockIdx.x * 64;
    int r0 = (tid >> 5) * 8;
    int c0 = (tid & 31) * 4;
    float acc[8][4] = {};
    for (int k0 = 0; k0 < IN_C; k0 += 64) {
        __syncthreads();
        {
            int col4 = (tid & 15) * 4;
            for (int rr = tid >> 4; rr < 64; rr += 16) {
                long long gr = row0 + rr;
                float4 v = make_float4(0.f, 0.f, 0.f, 0.f);
                if (gr < N) v = *(const float4*)&X[gr * IN_C + k0 + col4];
                *(float4*)&xs[rr][col4] = v;
            }
        }
        {
            int col4 = (tid & 31) * 4;
            for (int rr = tid >> 5; rr < 64; rr += 8)
                *(float4*)&ws[rr][col4] = *(const float4*)&W[(long long)(k0 + rr) * HID + col4];
        }
        __syncthreads();
        #pragma unroll 8
        for (int k = 0; k < 64; ++k) {
            float4 wb = *(const float4*)&ws[k][c0];
            #pragma unroll
            for (int i = 0; i < 8; ++i) {
                float xa = xs[r0 + i][k];
                acc[i][0] += xa * wb.x; acc[i][1] += xa * wb.y;
                acc[i][2] += xa * wb.z; acc[i][3] += xa * wb.w;
            }
        }
    }
    for (int i = 0; i < 8; ++i) {
        long long gr = row0 + r0 + i;
        if (gr < N)
            *(float4*)&H[gr * HID + c0] =
                make_float4(acc[i][0], acc[i][1], acc[i][2], acc[i][3]);
    }
}

// ---- GEMM2: H2[N,64] = relu(A[N,128] + b1) @ W2[128,64] --------------------
__global__ __launch_bounds__(256) void gemm2_kernel(const float* __restrict__ A,
                                                    const float* __restrict__ b1,
                                                    const float* __restrict__ W,
                                                    float* __restrict__ H, int N) {
    __shared__ float xs[64][68];
    __shared__ float ws[64][64];
    int tid = threadIdx.x;
    long long row0 = (long long)blockIdx.x * 64;
    int r0 = (tid >> 4) * 4;
    int c0 = (tid & 15) * 4;
    float acc[4][4] = {};
    for (int k0 = 0; k0 < HID; k0 += 64) {
        __syncthreads();
        {
            int col4 = (tid & 15) * 4;
            float4 bb = *(const float4*)&b1[k0 + col4];
            for (int rr = tid >> 4; rr < 64; rr += 16) {
                long long gr = row0 + rr;
                float4 v = make_float4(0.f, 0.f, 0.f, 0.f);
                if (gr < N) {
                    v = *(const float4*)&A[gr * HID + k0 + col4];
                    v.x = fmaxf(v.x + bb.x, 0.f); v.y = fmaxf(v.y + bb.y, 0.f);
                    v.z = fmaxf(v.z + bb.z, 0.f); v.w = fmaxf(v.w + bb.w, 0.f);
                }
                *(float4*)&xs[rr][col4] = v;
            }
        }
        {
            int col4 = (tid & 15) * 4;
            for (int rr = tid >> 4; rr < 64; rr += 16)
                *(float4*)&ws[rr][col4] = *(const float4*)&W[(long long)(k0 + rr) * OUTC + col4];
        }
        __syncthreads();
        #pragma unroll 8
        for (int k = 0; k < 64; ++k) {
            float4 wb = *(const float4*)&ws[k][c0];
            #pragma unroll
            for (int i = 0; i < 4; ++i) {
                float xa = xs[r0 + i][k];
                acc[i][0] += xa * wb.x; acc[i][1] += xa * wb.y;
                acc[i][2] += xa * wb.z; acc[i][3] += xa * wb.w;
            }
        }
    }
    for (int i = 0; i < 4; ++i) {
        long long gr = row0 + r0 + i;
        if (gr < N)
            *(float4*)&H[gr * OUTC + c0] =
                make_float4(acc[i][0], acc[i][1], acc[i][2], acc[i][3]);
    }
}

// ---- atomic-free segment aggregation: one wave per dst node ----------------
// out[n] = sum_{e in seg(n)} h[src_e]*dis[src_e]*dis[n] + h[n]*dis[n]^2 (+bias)
template <int F, bool BIAS>
__global__ void seg_agg_kernel(const float* __restrict__ Hin,
                               const float* __restrict__ dis,
                               const int* __restrict__ row_ptr,
                               const int* __restrict__ sorted_src,
                               const float* __restrict__ bias,
                               float* __restrict__ out, int N) {
    constexpr int PER = F / 64;
    long long wid = ((long long)blockIdx.x * blockDim.x + threadIdx.x) >> 6;
    int lane = threadIdx.x & 63;
    long long nw = ((long long)gridDim.x * blockDim.x) >> 6;
    for (long long n = wid; n < N; n += nw) {
        float dn = dis[n];
        float acc[PER];
        #pragma unroll
        for (int p = 0; p < PER; ++p)                       // self loop
            acc[p] = Hin[n * F + p * 64 + lane] * (dn * dn);
        int e0 = row_ptr[n], e1 = row_ptr[n + 1];
        for (int e = e0; e < e1; ++e) {
            int s = sorted_src[e];
            float nrm = dis[s] * dn;
            const float* hr = &Hin[(long long)s * F];
            #pragma unroll
            for (int p = 0; p < PER; ++p)
                acc[p] += hr[p * 64 + lane] * nrm;
        }
        #pragma unroll
        for (int p = 0; p < PER; ++p)
            out[n * F + p * 64 + lane] = BIAS ? acc[p] + bias[p * 64 + lane] : acc[p];
    }
}

extern "C" void kernel_launch(void* const* d_in, const int* in_sizes, int n_in,
                              void* d_out, int out_size, void* d_ws, size_t ws_size,
                              hipStream_t stream) {
    const float* x  = (const float*)d_in[0];
    const void*  ei = d_in[1];
    const float* W1 = (const float*)d_in[2];
    const float* b1 = (const float*)d_in[3];
    const float* W2 = (const float*)d_in[4];
    const float* b2 = (const float*)d_in[5];
    float* out = (float*)d_out;
    int N = in_sizes[0] / IN_C;    // 50000
    int E = in_sizes[1] / 2;       // 800000

    char* ws = (char*)d_ws;
    size_t off = 0;
    auto alloc = [&](size_t bytes) {
        void* p = ws + off;
        off += ((bytes + 255) / 256) * 256;
        return p;
    };
    int*   flag       = (int*)alloc(4);
    int*   degi       = (int*)alloc((size_t)N * 4);
    int*   row_ptr    = (int*)alloc(((size_t)N + 1) * 4);
    int*   cursor     = (int*)alloc((size_t)N * 4);
    float* dis        = (float*)alloc((size_t)N * 4);
    int*   sorted_src = (int*)alloc((size_t)E * 4);
    float* H1         = (float*)alloc((size_t)N * HID * 4);   // reused as H2
    float* AG1        = (float*)alloc((size_t)N * HID * 4);
    float* H2         = H1;  // H1 dead after seg_agg layer 1

    hipMemsetAsync(degi, 0, (size_t)N * 4, stream);

    detect_kernel<<<1, 64, 0, stream>>>((const unsigned long long*)ei, flag);
    degi_kernel<<<1024, 256, 0, stream>>>(ei, flag, degi, E);
    dis_kernel<<<(N + 255) / 256, 256, 0, stream>>>(degi, dis, N);
    scan_kernel<<<1, 1024, 0, stream>>>(degi, row_ptr, cursor, N);
    scatter_kernel<<<1024, 256, 0, stream>>>(ei, flag, cursor, sorted_src, E);
    gemm1_kernel<<<(N + 63) / 64, 256, 0, stream>>>(x, W1, H1, N);
    seg_agg_kernel<HID, false><<<(N * 64 + 255) / 256, 256, 0, stream>>>(
        H1, dis, row_ptr, sorted_src, nullptr, AG1, N);
    gemm2_kernel<<<(N + 63) / 64, 256, 0, stream>>>(AG1, b1, W2, H2, N);
    seg_agg_kernel<OUTC, true><<<(N * 64 + 255) / 256, 256, 0, stream>>>(
        H2, dis, row_ptr, sorted_src, b2, out, N);
}

// Round 3
// 348.421 us; speedup vs baseline: 2.0191x; 1.3118x over previous
//
#include <hip/hip_runtime.h>

// GCN 2-layer encoder: N=50000 nodes, E=800000 edges, 256 -> 128 -> 64.
// fp32 throughout. Round 3: parallel hierarchical scan (old single-block
// scan was 116us at 0.14% occupancy).

#define IN_C 256
#define HID 128
#define OUTC 64
#define SCAN_BLK 256

// ---- edge index access (int64 vs int32 detected at runtime) ----------------
__device__ __forceinline__ int edge_at(const void* ei, long long idx, int is32) {
    return is32 ? ((const int*)ei)[idx] : (int)((const long long*)ei)[idx];
}

__global__ void detect_kernel(const unsigned long long* ei, int* flag) {
    if (threadIdx.x == 0 && blockIdx.x == 0) {
        int is32 = 0;
        for (int i = 0; i < 64; ++i)
            if (ei[i] >> 32) { is32 = 1; break; }
        *flag = is32;  // 1 => data is int32 pairs, 0 => true int64
    }
}

// ---- integer degree histogram over dst -------------------------------------
__global__ void degi_kernel(const void* ei, const int* __restrict__ flag,
                            int* __restrict__ degi, int E) {
    int is32 = *flag;
    long long stride = (long long)gridDim.x * blockDim.x;
    for (long long e = (long long)blockIdx.x * blockDim.x + threadIdx.x; e < E; e += stride) {
        int d = edge_at(ei, (long long)E + e, is32);
        atomicAdd(&degi[d], 1);
    }
}

// ---- hierarchical exclusive scan: A) block sums ----------------------------
__global__ __launch_bounds__(SCAN_BLK) void scan_sums_kernel(const int* __restrict__ degi,
                                                             int* __restrict__ bsum, int N) {
    int i = blockIdx.x * SCAN_BLK + threadIdx.x;
    int v = (i < N) ? degi[i] : 0;
    #pragma unroll
    for (int d = 32; d > 0; d >>= 1) v += __shfl_down(v, d, 64);
    __shared__ int ws[4];
    if ((threadIdx.x & 63) == 0) ws[threadIdx.x >> 6] = v;
    __syncthreads();
    if (threadIdx.x == 0) bsum[blockIdx.x] = ws[0] + ws[1] + ws[2] + ws[3];
}

// ---- B) scan block sums (nb <= 256) ----------------------------------------
__global__ __launch_bounds__(SCAN_BLK) void scan_bsum_kernel(int* __restrict__ bsum, int nb) {
    __shared__ int sh[SCAN_BLK];
    int t = threadIdx.x;
    int v = (t < nb) ? bsum[t] : 0;
    sh[t] = v;
    __syncthreads();
    #pragma unroll
    for (int d = 1; d < SCAN_BLK; d <<= 1) {
        int add = (t >= d) ? sh[t - d] : 0;
        __syncthreads();
        sh[t] += add;
        __syncthreads();
    }
    if (t < nb) bsum[t] = sh[t] - v;  // exclusive
}

// ---- C) intra-block scan + emit row_ptr/cursor/dis -------------------------
__global__ __launch_bounds__(SCAN_BLK) void scan_emit_kernel(const int* __restrict__ degi,
                                                             const int* __restrict__ bsum,
                                                             int* __restrict__ row_ptr,
                                                             int* __restrict__ cursor,
                                                             float* __restrict__ dis, int N) {
    __shared__ int sh[SCAN_BLK];
    int t = threadIdx.x;
    int i = blockIdx.x * SCAN_BLK + t;
    int v = (i < N) ? degi[i] : 0;
    sh[t] = v;
    __syncthreads();
    #pragma unroll
    for (int d = 1; d < SCAN_BLK; d <<= 1) {
        int add = (t >= d) ? sh[t - d] : 0;
        __syncthreads();
        sh[t] += add;
        __syncthreads();
    }
    if (i < N) {
        int excl = bsum[blockIdx.x] + sh[t] - v;
        row_ptr[i] = excl;
        cursor[i] = excl;
        dis[i] = rsqrtf((float)v + 1.0f);  // +1 = self loop
        if (i == N - 1) row_ptr[N] = excl + v;  // = E
    }
}

// ---- scatter src ids into dst-sorted order ---------------------------------
__global__ void scatter_kernel(const void* ei, const int* __restrict__ flag,
                               int* __restrict__ cursor, int* __restrict__ sorted_src,
                               int E) {
    int is32 = *flag;
    long long stride = (long long)gridDim.x * blockDim.x;
    for (long long e = (long long)blockIdx.x * blockDim.x + threadIdx.x; e < E; e += stride) {
        int s = edge_at(ei, e, is32);
        int d = edge_at(ei, (long long)E + e, is32);
        int pos = atomicAdd(&cursor[d], 1);
        sorted_src[pos] = s;
    }
}

// ---- GEMM1: H[N,128] = X[N,256] @ W1[256,128] ------------------------------
__global__ __launch_bounds__(256) void gemm1_kernel(const float* __restrict__ X,
                                                    const float* __restrict__ W,
                                                    float* __restrict__ H, int N) {
    __shared__ float xs[64][68];
    __shared__ float ws[64][128];
    int tid = threadIdx.x;
    long long row0 = (long long)blockIdx.x * 64;
    int r0 = (tid >> 5) * 8;
    int c0 = (tid & 31) * 4;
    float acc[8][4] = {};
    for (int k0 = 0; k0 < IN_C; k0 += 64) {
        __syncthreads();
        {
            int col4 = (tid & 15) * 4;
            for (int rr = tid >> 4; rr < 64; rr += 16) {
                long long gr = row0 + rr;
                float4 v = make_float4(0.f, 0.f, 0.f, 0.f);
                if (gr < N) v = *(const float4*)&X[gr * IN_C + k0 + col4];
                *(float4*)&xs[rr][col4] = v;
            }
        }
        {
            int col4 = (tid & 31) * 4;
            for (int rr = tid >> 5; rr < 64; rr += 8)
                *(float4*)&ws[rr][col4] = *(const float4*)&W[(long long)(k0 + rr) * HID + col4];
        }
        __syncthreads();
        #pragma unroll 8
        for (int k = 0; k < 64; ++k) {
            float4 wb = *(const float4*)&ws[k][c0];
            #pragma unroll
            for (int i = 0; i < 8; ++i) {
                float xa = xs[r0 + i][k];
                acc[i][0] += xa * wb.x; acc[i][1] += xa * wb.y;
                acc[i][2] += xa * wb.z; acc[i][3] += xa * wb.w;
            }
        }
    }
    for (int i = 0; i < 8; ++i) {
        long long gr = row0 + r0 + i;
        if (gr < N)
            *(float4*)&H[gr * HID + c0] =
                make_float4(acc[i][0], acc[i][1], acc[i][2], acc[i][3]);
    }
}

// ---- GEMM2: H2[N,64] = relu(A[N,128] + b1) @ W2[128,64] --------------------
__global__ __launch_bounds__(256) void gemm2_kernel(const float* __restrict__ A,
                                                    const float* __restrict__ b1,
                                                    const float* __restrict__ W,
                                                    float* __restrict__ H, int N) {
    __shared__ float xs[64][68];
    __shared__ float ws[64][64];
    int tid = threadIdx.x;
    long long row0 = (long long)blockIdx.x * 64;
    int r0 = (tid >> 4) * 4;
    int c0 = (tid & 15) * 4;
    float acc[4][4] = {};
    for (int k0 = 0; k0 < HID; k0 += 64) {
        __syncthreads();
        {
            int col4 = (tid & 15) * 4;
            float4 bb = *(const float4*)&b1[k0 + col4];
            for (int rr = tid >> 4; rr < 64; rr += 16) {
                long long gr = row0 + rr;
                float4 v = make_float4(0.f, 0.f, 0.f, 0.f);
                if (gr < N) {
                    v = *(const float4*)&A[gr * HID + k0 + col4];
                    v.x = fmaxf(v.x + bb.x, 0.f); v.y = fmaxf(v.y + bb.y, 0.f);
                    v.z = fmaxf(v.z + bb.z, 0.f); v.w = fmaxf(v.w + bb.w, 0.f);
                }
                *(float4*)&xs[rr][col4] = v;
            }
        }
        {
            int col4 = (tid & 15) * 4;
            for (int rr = tid >> 4; rr < 64; rr += 16)
                *(float4*)&ws[rr][col4] = *(const float4*)&W[(long long)(k0 + rr) * OUTC + col4];
        }
        __syncthreads();
        #pragma unroll 8
        for (int k = 0; k < 64; ++k) {
            float4 wb = *(const float4*)&ws[k][c0];
            #pragma unroll
            for (int i = 0; i < 4; ++i) {
                float xa = xs[r0 + i][k];
                acc[i][0] += xa * wb.x; acc[i][1] += xa * wb.y;
                acc[i][2] += xa * wb.z; acc[i][3] += xa * wb.w;
            }
        }
    }
    for (int i = 0; i < 4; ++i) {
        long long gr = row0 + r0 + i;
        if (gr < N)
            *(float4*)&H[gr * OUTC + c0] =
                make_float4(acc[i][0], acc[i][1], acc[i][2], acc[i][3]);
    }
}

// ---- atomic-free segment aggregation: one wave per dst node ----------------
template <int F, bool BIAS>
__global__ void seg_agg_kernel(const float* __restrict__ Hin,
                               const float* __restrict__ dis,
                               const int* __restrict__ row_ptr,
                               const int* __restrict__ sorted_src,
                               const float* __restrict__ bias,
                               float* __restrict__ out, int N) {
    constexpr int PER = F / 64;
    long long wid = ((long long)blockIdx.x * blockDim.x + threadIdx.x) >> 6;
    int lane = threadIdx.x & 63;
    long long nw = ((long long)gridDim.x * blockDim.x) >> 6;
    for (long long n = wid; n < N; n += nw) {
        float dn = dis[n];
        float acc[PER];
        #pragma unroll
        for (int p = 0; p < PER; ++p)                       // self loop
            acc[p] = Hin[n * F + p * 64 + lane] * (dn * dn);
        int e0 = row_ptr[n], e1 = row_ptr[n + 1];
        for (int e = e0; e < e1; ++e) {
            int s = sorted_src[e];
            float nrm = dis[s] * dn;
            const float* hr = &Hin[(long long)s * F];
            #pragma unroll
            for (int p = 0; p < PER; ++p)
                acc[p] += hr[p * 64 + lane] * nrm;
        }
        #pragma unroll
        for (int p = 0; p < PER; ++p)
            out[n * F + p * 64 + lane] = BIAS ? acc[p] + bias[p * 64 + lane] : acc[p];
    }
}

extern "C" void kernel_launch(void* const* d_in, const int* in_sizes, int n_in,
                              void* d_out, int out_size, void* d_ws, size_t ws_size,
                              hipStream_t stream) {
    const float* x  = (const float*)d_in[0];
    const void*  ei = d_in[1];
    const float* W1 = (const float*)d_in[2];
    const float* b1 = (const float*)d_in[3];
    const float* W2 = (const float*)d_in[4];
    const float* b2 = (const float*)d_in[5];
    float* out = (float*)d_out;
    int N = in_sizes[0] / IN_C;    // 50000
    int E = in_sizes[1] / 2;       // 800000

    char* ws = (char*)d_ws;
    size_t off = 0;
    auto alloc = [&](size_t bytes) {
        void* p = ws + off;
        off += ((bytes + 255) / 256) * 256;
        return p;
    };
    int nb = (N + SCAN_BLK - 1) / SCAN_BLK;  // 196
    int*   flag       = (int*)alloc(4);
    int*   degi       = (int*)alloc((size_t)N * 4);
    int*   bsum       = (int*)alloc((size_t)nb * 4);
    int*   row_ptr    = (int*)alloc(((size_t)N + 1) * 4);
    int*   cursor     = (int*)alloc((size_t)N * 4);
    float* dis        = (float*)alloc((size_t)N * 4);
    int*   sorted_src = (int*)alloc((size_t)E * 4);
    float* H1         = (float*)alloc((size_t)N * HID * 4);   // reused as H2
    float* AG1        = (float*)alloc((size_t)N * HID * 4);
    float* H2         = H1;  // H1 dead after seg_agg layer 1

    hipMemsetAsync(degi, 0, (size_t)N * 4, stream);

    detect_kernel<<<1, 64, 0, stream>>>((const unsigned long long*)ei, flag);
    degi_kernel<<<1024, 256, 0, stream>>>(ei, flag, degi, E);
    scan_sums_kernel<<<nb, SCAN_BLK, 0, stream>>>(degi, bsum, N);
    scan_bsum_kernel<<<1, SCAN_BLK, 0, stream>>>(bsum, nb);
    scan_emit_kernel<<<nb, SCAN_BLK, 0, stream>>>(degi, bsum, row_ptr, cursor, dis, N);
    scatter_kernel<<<1024, 256, 0, stream>>>(ei, flag, cursor, sorted_src, E);
    gemm1_kernel<<<(N + 63) / 64, 256, 0, stream>>>(x, W1, H1, N);
    seg_agg_kernel<HID, false><<<(N * 64 + 255) / 256, 256, 0, stream>>>(
        H1, dis, row_ptr, sorted_src, nullptr, AG1, N);
    gemm2_kernel<<<(N + 63) / 64, 256, 0, stream>>>(AG1, b1, W2, H2, N);
    seg_agg_kernel<OUTC, true><<<(N * 64 + 255) / 256, 256, 0, stream>>>(
        H2, dis, row_ptr, sorted_src, b2, out, N);
}

// Round 4
// 294.595 us; speedup vs baseline: 2.3880x; 1.1827x over previous
//
#include <hip/hip_runtime.h>

// GCN 2-layer encoder: N=50000 nodes, E=800000 edges, 256 -> 128 -> 64.
// Round 4: GEMMs via bf16 MFMA with hi/lo split (fp32-level precision,
// 3 MFMA products). Aggregation/scan/scatter unchanged from round 3.

#define IN_C 256
#define HID 128
#define OUTC 64
#define SCAN_BLK 256

typedef __attribute__((ext_vector_type(8))) short short8;
typedef __attribute__((ext_vector_type(4))) float f32x4;

// ---- fp32 -> bf16 hi/lo split ----------------------------------------------
// hi = truncate(x) (top 16 bits), lo = rtn(x - hi). x == hi + lo to ~2^-17 rel.
__device__ __forceinline__ void bf16split(float f, ushort& h, ushort& l) {
    unsigned u = __float_as_uint(f);
    h = (ushort)(u >> 16);
    float hf = __uint_as_float(u & 0xFFFF0000u);
    unsigned v = __float_as_uint(f - hf);
    l = (ushort)((v + 0x7FFF + ((v >> 16) & 1)) >> 16);
}

// ---- swizzled LDS addressing for [row][64 k] bf16 tiles (128 B rows) -------
// byte ^= (row&7)<<4 spreads the 128B-stride rows across 8 16B slots: the
// 16-lane same-column frag read goes from 16-way conflict to free (2-way).
__device__ __forceinline__ void* lds_addr(void* base, int row, int kelem) {
    int byte = row * 128 + kelem * 2;
    byte ^= (row & 7) << 4;
    return (char*)base + byte;
}

// ---- edge index access (int64 vs int32 detected at runtime) ----------------
__device__ __forceinline__ int edge_at(const void* ei, long long idx, int is32) {
    return is32 ? ((const int*)ei)[idx] : (int)((const long long*)ei)[idx];
}

__global__ void detect_kernel(const unsigned long long* ei, int* flag) {
    if (threadIdx.x == 0 && blockIdx.x == 0) {
        int is32 = 0;
        for (int i = 0; i < 64; ++i)
            if (ei[i] >> 32) { is32 = 1; break; }
        *flag = is32;
    }
}

// ---- weight pre-transpose + split: W[k][n] -> WT_hi/lo[n][k] ---------------
__global__ void wtrans_kernel(const float* __restrict__ W1, const float* __restrict__ W2,
                              ushort* __restrict__ w1h, ushort* __restrict__ w1l,
                              ushort* __restrict__ w2h, ushort* __restrict__ w2l) {
    int id = blockIdx.x * blockDim.x + threadIdx.x;
    if (id < HID * IN_C) {                     // 128 n x 256 k
        int n = id >> 8, k = id & 255;
        ushort h, l; bf16split(W1[k * HID + n], h, l);
        w1h[id] = h; w1l[id] = l;
    }
    if (id < OUTC * HID) {                     // 64 n x 128 k
        int n = id >> 7, k = id & 127;
        ushort h, l; bf16split(W2[k * OUTC + n], h, l);
        w2h[id] = h; w2l[id] = l;
    }
}

// ---- integer degree histogram over dst -------------------------------------
__global__ void degi_kernel(const void* ei, const int* __restrict__ flag,
                            int* __restrict__ degi, int E) {
    int is32 = *flag;
    long long stride = (long long)gridDim.x * blockDim.x;
    for (long long e = (long long)blockIdx.x * blockDim.x + threadIdx.x; e < E; e += stride) {
        int d = edge_at(ei, (long long)E + e, is32);
        atomicAdd(&degi[d], 1);
    }
}

// ---- hierarchical exclusive scan: A) block sums ----------------------------
__global__ __launch_bounds__(SCAN_BLK) void scan_sums_kernel(const int* __restrict__ degi,
                                                             int* __restrict__ bsum, int N) {
    int i = blockIdx.x * SCAN_BLK + threadIdx.x;
    int v = (i < N) ? degi[i] : 0;
    #pragma unroll
    for (int d = 32; d > 0; d >>= 1) v += __shfl_down(v, d, 64);
    __shared__ int ws[4];
    if ((threadIdx.x & 63) == 0) ws[threadIdx.x >> 6] = v;
    __syncthreads();
    if (threadIdx.x == 0) bsum[blockIdx.x] = ws[0] + ws[1] + ws[2] + ws[3];
}

// ---- B) scan block sums (nb <= 256) ----------------------------------------
__global__ __launch_bounds__(SCAN_BLK) void scan_bsum_kernel(int* __restrict__ bsum, int nb) {
    __shared__ int sh[SCAN_BLK];
    int t = threadIdx.x;
    int v = (t < nb) ? bsum[t] : 0;
    sh[t] = v;
    __syncthreads();
    #pragma unroll
    for (int d = 1; d < SCAN_BLK; d <<= 1) {
        int add = (t >= d) ? sh[t - d] : 0;
        __syncthreads();
        sh[t] += add;
        __syncthreads();
    }
    if (t < nb) bsum[t] = sh[t] - v;  // exclusive
}

// ---- C) intra-block scan + emit row_ptr/cursor/dis -------------------------
__global__ __launch_bounds__(SCAN_BLK) void scan_emit_kernel(const int* __restrict__ degi,
                                                             const int* __restrict__ bsum,
                                                             int* __restrict__ row_ptr,
                                                             int* __restrict__ cursor,
                                                             float* __restrict__ dis, int N) {
    __shared__ int sh[SCAN_BLK];
    int t = threadIdx.x;
    int i = blockIdx.x * SCAN_BLK + t;
    int v = (i < N) ? degi[i] : 0;
    sh[t] = v;
    __syncthreads();
    #pragma unroll
    for (int d = 1; d < SCAN_BLK; d <<= 1) {
        int add = (t >= d) ? sh[t - d] : 0;
        __syncthreads();
        sh[t] += add;
        __syncthreads();
    }
    if (i < N) {
        int excl = bsum[blockIdx.x] + sh[t] - v;
        row_ptr[i] = excl;
        cursor[i] = excl;
        dis[i] = rsqrtf((float)v + 1.0f);  // +1 = self loop
        if (i == N - 1) row_ptr[N] = excl + v;  // = E
    }
}

// ---- scatter src ids into dst-sorted order ---------------------------------
__global__ void scatter_kernel(const void* ei, const int* __restrict__ flag,
                               int* __restrict__ cursor, int* __restrict__ sorted_src,
                               int E) {
    int is32 = *flag;
    long long stride = (long long)gridDim.x * blockDim.x;
    for (long long e = (long long)blockIdx.x * blockDim.x + threadIdx.x; e < E; e += stride) {
        int s = edge_at(ei, e, is32);
        int d = edge_at(ei, (long long)E + e, is32);
        int pos = atomicAdd(&cursor[d], 1);
        sorted_src[pos] = s;
    }
}

// ---- GEMM1 (MFMA): H[N,128] = X[N,256] @ W1[256,128] -----------------------
// A-frag: lane reads A[m0+(l&15)][kk*32+(l>>4)*8 .. +7] (verified m92/m97).
// B-frag: same pattern from WT[n][k]. C/D: row=(l>>4)*4+reg, col=l&15.
__global__ __launch_bounds__(256) void gemm1_mfma(const float* __restrict__ X,
                                                  const ushort* __restrict__ WTh,
                                                  const ushort* __restrict__ WTl,
                                                  float* __restrict__ H, int N) {
    __shared__ ushort XH[64 * 64], XL[64 * 64];     // 8 KB each
    __shared__ ushort WH[128 * 64], WL[128 * 64];   // 16 KB each
    int t = threadIdx.x;
    int lane = t & 63, w = t >> 6;
    int m_off = (w >> 1) * 32, n_off = (w & 1) * 64;
    long long row0 = (long long)blockIdx.x * 64;
    f32x4 acc[2][4] = {};
    for (int k0 = 0; k0 < IN_C; k0 += 64) {
        __syncthreads();
        {   // stage X tile: 64 rows x 64 k, convert fp32 -> hi/lo bf16
            int xr = t >> 4, xc = (t & 15) * 4;
            #pragma unroll
            for (int p = 0; p < 4; ++p) {
                int row = xr + p * 16;
                long long gr = row0 + row;
                float4 v = make_float4(0.f, 0.f, 0.f, 0.f);
                if (gr < N) v = *(const float4*)&X[gr * IN_C + k0 + xc];
                ushort4 h4, l4;
                bf16split(v.x, h4.x, l4.x); bf16split(v.y, h4.y, l4.y);
                bf16split(v.z, h4.z, l4.z); bf16split(v.w, h4.w, l4.w);
                *(ushort4*)lds_addr(XH, row, xc) = h4;
                *(ushort4*)lds_addr(XL, row, xc) = l4;
            }
        }
        {   // stage WT tiles: 128 n x 64 k per plane, pre-split in global
            int wn = t >> 3, wk = (t & 7) * 8;
            #pragma unroll
            for (int p = 0; p < 4; ++p) {
                int n = wn + p * 32;
                *(short8*)lds_addr(WH, n, wk) = *(const short8*)&WTh[n * IN_C + k0 + wk];
                *(short8*)lds_addr(WL, n, wk) = *(const short8*)&WTl[n * IN_C + k0 + wk];
            }
        }
        __syncthreads();
        #pragma unroll
        for (int kk = 0; kk < 2; ++kk) {
            int ke = kk * 32 + (lane >> 4) * 8;
            short8 ah[2], al[2], bh[4], bl[4];
            #pragma unroll
            for (int mi = 0; mi < 2; ++mi) {
                int r = m_off + mi * 16 + (lane & 15);
                ah[mi] = *(short8*)lds_addr(XH, r, ke);
                al[mi] = *(short8*)lds_addr(XL, r, ke);
            }
            #pragma unroll
            for (int ni = 0; ni < 4; ++ni) {
                int r = n_off + ni * 16 + (lane & 15);
                bh[ni] = *(short8*)lds_addr(WH, r, ke);
                bl[ni] = *(short8*)lds_addr(WL, r, ke);
            }
            #pragma unroll
            for (int mi = 0; mi < 2; ++mi)
                #pragma unroll
                for (int ni = 0; ni < 4; ++ni) {
                    acc[mi][ni] = __builtin_amdgcn_mfma_f32_16x16x32_bf16(ah[mi], bh[ni], acc[mi][ni], 0, 0, 0);
                    acc[mi][ni] = __builtin_amdgcn_mfma_f32_16x16x32_bf16(ah[mi], bl[ni], acc[mi][ni], 0, 0, 0);
                    acc[mi][ni] = __builtin_amdgcn_mfma_f32_16x16x32_bf16(al[mi], bh[ni], acc[mi][ni], 0, 0, 0);
                }
        }
    }
    int cr = (lane >> 4) * 4, cc = lane & 15;
    #pragma unroll
    for (int mi = 0; mi < 2; ++mi)
        #pragma unroll
        for (int j = 0; j < 4; ++j) {
            long long gr = row0 + m_off + mi * 16 + cr + j;
            if (gr < N)
                #pragma unroll
                for (int ni = 0; ni < 4; ++ni)
                    H[gr * HID + n_off + ni * 16 + cc] = acc[mi][ni][j];
        }
}

// ---- GEMM2 (MFMA): H2[N,64] = relu(AG1[N,128]+b1) @ W2[128,64] -------------
__global__ __launch_bounds__(256) void gemm2_mfma(const float* __restrict__ A,
                                                  const float* __restrict__ b1,
                                                  const ushort* __restrict__ WTh,
                                                  const ushort* __restrict__ WTl,
                                                  float* __restrict__ H, int N) {
    __shared__ ushort AH[64 * 64], AL[64 * 64];     // 8 KB each
    __shared__ ushort WH[64 * 64], WL[64 * 64];     // 8 KB each
    int t = threadIdx.x;
    int lane = t & 63, w = t >> 6;
    int m_off = (w >> 1) * 32, n_off = (w & 1) * 32;
    long long row0 = (long long)blockIdx.x * 64;
    f32x4 acc[2][2] = {};
    for (int k0 = 0; k0 < HID; k0 += 64) {
        __syncthreads();
        {   // stage A tile with fused +b1, relu, hi/lo split
            int xr = t >> 4, xc = (t & 15) * 4;
            float4 bb = *(const float4*)&b1[k0 + xc];
            #pragma unroll
            for (int p = 0; p < 4; ++p) {
                int row = xr + p * 16;
                long long gr = row0 + row;
                float4 v = make_float4(0.f, 0.f, 0.f, 0.f);
                if (gr < N) {
                    v = *(const float4*)&A[gr * HID + k0 + xc];
                    v.x = fmaxf(v.x + bb.x, 0.f); v.y = fmaxf(v.y + bb.y, 0.f);
                    v.z = fmaxf(v.z + bb.z, 0.f); v.w = fmaxf(v.w + bb.w, 0.f);
                }
                ushort4 h4, l4;
                bf16split(v.x, h4.x, l4.x); bf16split(v.y, h4.y, l4.y);
                bf16split(v.z, h4.z, l4.z); bf16split(v.w, h4.w, l4.w);
                *(ushort4*)lds_addr(AH, row, xc) = h4;
                *(ushort4*)lds_addr(AL, row, xc) = l4;
            }
        }
        {   // stage W2T tiles: 64 n x 64 k per plane
            int wn = t >> 3, wk = (t & 7) * 8;
            #pragma unroll
            for (int p = 0; p < 2; ++p) {
                int n = wn + p * 32;
                *(short8*)lds_addr(WH, n, wk) = *(const short8*)&WTh[n * HID + k0 + wk];
                *(short8*)lds_addr(WL, n, wk) = *(const short8*)&WTl[n * HID + k0 + wk];
            }
        }
        __syncthreads();
        #pragma unroll
        for (int kk = 0; kk < 2; ++kk) {
            int ke = kk * 32 + (lane >> 4) * 8;
            short8 ah[2], al[2], bh[2], bl[2];
            #pragma unroll
            for (int mi = 0; mi < 2; ++mi) {
                int r = m_off + mi * 16 + (lane & 15);
                ah[mi] = *(short8*)lds_addr(AH, r, ke);
                al[mi] = *(short8*)lds_addr(AL, r, ke);
            }
            #pragma unroll
            for (int ni = 0; ni < 2; ++ni) {
                int r = n_off + ni * 16 + (lane & 15);
                bh[ni] = *(short8*)lds_addr(WH, r, ke);
                bl[ni] = *(short8*)lds_addr(WL, r, ke);
            }
            #pragma unroll
            for (int mi = 0; mi < 2; ++mi)
                #pragma unroll
                for (int ni = 0; ni < 2; ++ni) {
                    acc[mi][ni] = __builtin_amdgcn_mfma_f32_16x16x32_bf16(ah[mi], bh[ni], acc[mi][ni], 0, 0, 0);
                    acc[mi][ni] = __builtin_amdgcn_mfma_f32_16x16x32_bf16(ah[mi], bl[ni], acc[mi][ni], 0, 0, 0);
                    acc[mi][ni] = __builtin_amdgcn_mfma_f32_16x16x32_bf16(al[mi], bh[ni], acc[mi][ni], 0, 0, 0);
                }
        }
    }
    int cr = (lane >> 4) * 4, cc = lane & 15;
    #pragma unroll
    for (int mi = 0; mi < 2; ++mi)
        #pragma unroll
        for (int j = 0; j < 4; ++j) {
            long long gr = row0 + m_off + mi * 16 + cr + j;
            if (gr < N)
                #pragma unroll
                for (int ni = 0; ni < 2; ++ni)
                    H[gr * OUTC + n_off + ni * 16 + cc] = acc[mi][ni][j];
        }
}

// ---- atomic-free segment aggregation: one wave per dst node ----------------
template <int F, bool BIAS>
__global__ void seg_agg_kernel(const float* __restrict__ Hin,
                               const float* __restrict__ dis,
                               const int* __restrict__ row_ptr,
                               const int* __restrict__ sorted_src,
                               const float* __restrict__ bias,
                               float* __restrict__ out, int N) {
    constexpr int PER = F / 64;
    long long wid = ((long long)blockIdx.x * blockDim.x + threadIdx.x) >> 6;
    int lane = threadIdx.x & 63;
    long long nw = ((long long)gridDim.x * blockDim.x) >> 6;
    for (long long n = wid; n < N; n += nw) {
        float dn = dis[n];
        float acc[PER];
        #pragma unroll
        for (int p = 0; p < PER; ++p)                       // self loop
            acc[p] = Hin[n * F + p * 64 + lane] * (dn * dn);
        int e0 = row_ptr[n], e1 = row_ptr[n + 1];
        for (int e = e0; e < e1; ++e) {
            int s = sorted_src[e];
            float nrm = dis[s] * dn;
            const float* hr = &Hin[(long long)s * F];
            #pragma unroll
            for (int p = 0; p < PER; ++p)
                acc[p] += hr[p * 64 + lane] * nrm;
        }
        #pragma unroll
        for (int p = 0; p < PER; ++p)
            out[n * F + p * 64 + lane] = BIAS ? acc[p] + bias[p * 64 + lane] : acc[p];
    }
}

extern "C" void kernel_launch(void* const* d_in, const int* in_sizes, int n_in,
                              void* d_out, int out_size, void* d_ws, size_t ws_size,
                              hipStream_t stream) {
    const float* x  = (const float*)d_in[0];
    const void*  ei = d_in[1];
    const float* W1 = (const float*)d_in[2];
    const float* b1 = (const float*)d_in[3];
    const float* W2 = (const float*)d_in[4];
    const float* b2 = (const float*)d_in[5];
    float* out = (float*)d_out;
    int N = in_sizes[0] / IN_C;    // 50000
    int E = in_sizes[1] / 2;       // 800000

    char* ws = (char*)d_ws;
    size_t off = 0;
    auto alloc = [&](size_t bytes) {
        void* p = ws + off;
        off += ((bytes + 255) / 256) * 256;
        return p;
    };
    int nb = (N + SCAN_BLK - 1) / SCAN_BLK;  // 196
    int*    flag       = (int*)alloc(4);
    int*    degi       = (int*)alloc((size_t)N * 4);
    int*    bsum       = (int*)alloc((size_t)nb * 4);
    int*    row_ptr    = (int*)alloc(((size_t)N + 1) * 4);
    int*    cursor     = (int*)alloc((size_t)N * 4);
    float*  dis        = (float*)alloc((size_t)N * 4);
    int*    sorted_src = (int*)alloc((size_t)E * 4);
    ushort* w1h        = (ushort*)alloc((size_t)HID * IN_C * 2);
    ushort* w1l        = (ushort*)alloc((size_t)HID * IN_C * 2);
    ushort* w2h        = (ushort*)alloc((size_t)OUTC * HID * 2);
    ushort* w2l        = (ushort*)alloc((size_t)OUTC * HID * 2);
    float*  H1         = (float*)alloc((size_t)N * HID * 4);   // reused as H2
    float*  AG1        = (float*)alloc((size_t)N * HID * 4);
    float*  H2         = H1;  // H1 dead after seg_agg layer 1

    hipMemsetAsync(degi, 0, (size_t)N * 4, stream);

    detect_kernel<<<1, 64, 0, stream>>>((const unsigned long long*)ei, flag);
    wtrans_kernel<<<(HID * IN_C + 255) / 256, 256, 0, stream>>>(W1, W2, w1h, w1l, w2h, w2l);
    degi_kernel<<<1024, 256, 0, stream>>>(ei, flag, degi, E);
    scan_sums_kernel<<<nb, SCAN_BLK, 0, stream>>>(degi, bsum, N);
    scan_bsum_kernel<<<1, SCAN_BLK, 0, stream>>>(bsum, nb);
    scan_emit_kernel<<<nb, SCAN_BLK, 0, stream>>>(degi, bsum, row_ptr, cursor, dis, N);
    scatter_kernel<<<1024, 256, 0, stream>>>(ei, flag, cursor, sorted_src, E);
    gemm1_mfma<<<(N + 63) / 64, 256, 0, stream>>>(x, w1h, w1l, H1, N);
    seg_agg_kernel<HID, false><<<(N * 64 + 255) / 256, 256, 0, stream>>>(
        H1, dis, row_ptr, sorted_src, nullptr, AG1, N);
    gemm2_mfma<<<(N + 63) / 64, 256, 0, stream>>>(AG1, b1, w2h, w2l, H2, N);
    seg_agg_kernel<OUTC, true><<<(N * 64 + 255) / 256, 256, 0, stream>>>(
        H2, dis, row_ptr, sorted_src, b2, out, N);
}

// Round 5
// 283.956 us; speedup vs baseline: 2.4775x; 1.0375x over previous
//
#include <hip/hip_runtime.h>

// GCN 2-layer encoder: N=50000 nodes, E=800000 edges, 256 -> 128 -> 64.
// Round 5: bf16 hidden states for the edge gathers (halves seg_agg traffic),
// precomputed per-edge norms. GEMMs via bf16-MFMA hi/lo split (fp32 accuracy).

#define IN_C 256
#define HID 128
#define OUTC 64
#define SCAN_BLK 256

typedef __attribute__((ext_vector_type(8))) short short8;
typedef __attribute__((ext_vector_type(4))) float f32x4;

// ---- fp32 -> bf16 hi/lo split (exact to ~2^-17 rel) ------------------------
__device__ __forceinline__ void bf16split(float f, ushort& h, ushort& l) {
    unsigned u = __float_as_uint(f);
    h = (ushort)(u >> 16);
    float hf = __uint_as_float(u & 0xFFFF0000u);
    unsigned v = __float_as_uint(f - hf);
    l = (ushort)((v + 0x7FFF + ((v >> 16) & 1)) >> 16);
}

// fp32 -> bf16 round-to-nearest-even
__device__ __forceinline__ ushort f2bf(float f) {
    unsigned u = __float_as_uint(f);
    return (ushort)((u + 0x7FFF + ((u >> 16) & 1)) >> 16);
}
__device__ __forceinline__ float bf2f(ushort u) {
    return __uint_as_float((unsigned)u << 16);
}

// ---- swizzled LDS addressing for [row][64 k] bf16 tiles (128 B rows) -------
__device__ __forceinline__ void* lds_addr(void* base, int row, int kelem) {
    int byte = row * 128 + kelem * 2;
    byte ^= (row & 7) << 4;
    return (char*)base + byte;
}

// ---- edge index access (int64 vs int32 detected at runtime) ----------------
__device__ __forceinline__ int edge_at(const void* ei, long long idx, int is32) {
    return is32 ? ((const int*)ei)[idx] : (int)((const long long*)ei)[idx];
}

__global__ void detect_kernel(const unsigned long long* ei, int* flag) {
    if (threadIdx.x == 0 && blockIdx.x == 0) {
        int is32 = 0;
        for (int i = 0; i < 64; ++i)
            if (ei[i] >> 32) { is32 = 1; break; }
        *flag = is32;
    }
}

// ---- weight pre-transpose + split: W[k][n] -> WT_hi/lo[n][k] ---------------
__global__ void wtrans_kernel(const float* __restrict__ W1, const float* __restrict__ W2,
                              ushort* __restrict__ w1h, ushort* __restrict__ w1l,
                              ushort* __restrict__ w2h, ushort* __restrict__ w2l) {
    int id = blockIdx.x * blockDim.x + threadIdx.x;
    if (id < HID * IN_C) {                     // 128 n x 256 k
        int n = id >> 8, k = id & 255;
        ushort h, l; bf16split(W1[k * HID + n], h, l);
        w1h[id] = h; w1l[id] = l;
    }
    if (id < OUTC * HID) {                     // 64 n x 128 k
        int n = id >> 7, k = id & 127;
        ushort h, l; bf16split(W2[k * OUTC + n], h, l);
        w2h[id] = h; w2l[id] = l;
    }
}

// ---- integer degree histogram over dst -------------------------------------
__global__ void degi_kernel(const void* ei, const int* __restrict__ flag,
                            int* __restrict__ degi, int E) {
    int is32 = *flag;
    long long stride = (long long)gridDim.x * blockDim.x;
    for (long long e = (long long)blockIdx.x * blockDim.x + threadIdx.x; e < E; e += stride) {
        int d = edge_at(ei, (long long)E + e, is32);
        atomicAdd(&degi[d], 1);
    }
}

// ---- hierarchical exclusive scan -------------------------------------------
__global__ __launch_bounds__(SCAN_BLK) void scan_sums_kernel(const int* __restrict__ degi,
                                                             int* __restrict__ bsum, int N) {
    int i = blockIdx.x * SCAN_BLK + threadIdx.x;
    int v = (i < N) ? degi[i] : 0;
    #pragma unroll
    for (int d = 32; d > 0; d >>= 1) v += __shfl_down(v, d, 64);
    __shared__ int ws[4];
    if ((threadIdx.x & 63) == 0) ws[threadIdx.x >> 6] = v;
    __syncthreads();
    if (threadIdx.x == 0) bsum[blockIdx.x] = ws[0] + ws[1] + ws[2] + ws[3];
}

__global__ __launch_bounds__(SCAN_BLK) void scan_bsum_kernel(int* __restrict__ bsum, int nb) {
    __shared__ int sh[SCAN_BLK];
    int t = threadIdx.x;
    int v = (t < nb) ? bsum[t] : 0;
    sh[t] = v;
    __syncthreads();
    #pragma unroll
    for (int d = 1; d < SCAN_BLK; d <<= 1) {
        int add = (t >= d) ? sh[t - d] : 0;
        __syncthreads();
        sh[t] += add;
        __syncthreads();
    }
    if (t < nb) bsum[t] = sh[t] - v;  // exclusive
}

__global__ __launch_bounds__(SCAN_BLK) void scan_emit_kernel(const int* __restrict__ degi,
                                                             const int* __restrict__ bsum,
                                                             int* __restrict__ row_ptr,
                                                             int* __restrict__ cursor,
                                                             float* __restrict__ dis, int N) {
    __shared__ int sh[SCAN_BLK];
    int t = threadIdx.x;
    int i = blockIdx.x * SCAN_BLK + t;
    int v = (i < N) ? degi[i] : 0;
    sh[t] = v;
    __syncthreads();
    #pragma unroll
    for (int d = 1; d < SCAN_BLK; d <<= 1) {
        int add = (t >= d) ? sh[t - d] : 0;
        __syncthreads();
        sh[t] += add;
        __syncthreads();
    }
    if (i < N) {
        int excl = bsum[blockIdx.x] + sh[t] - v;
        row_ptr[i] = excl;
        cursor[i] = excl;
        dis[i] = rsqrtf((float)v + 1.0f);  // +1 = self loop
        if (i == N - 1) row_ptr[N] = excl + v;  // = E
    }
}

// ---- scatter src ids + edge norms into dst-sorted order --------------------
__global__ void scatter_kernel(const void* ei, const int* __restrict__ flag,
                               const float* __restrict__ dis,
                               int* __restrict__ cursor, int* __restrict__ sorted_src,
                               float* __restrict__ snrm, int E) {
    int is32 = *flag;
    long long stride = (long long)gridDim.x * blockDim.x;
    for (long long e = (long long)blockIdx.x * blockDim.x + threadIdx.x; e < E; e += stride) {
        int s = edge_at(ei, e, is32);
        int d = edge_at(ei, (long long)E + e, is32);
        int pos = atomicAdd(&cursor[d], 1);
        sorted_src[pos] = s;
        snrm[pos] = dis[s] * dis[d];
    }
}

// ---- GEMM1 (MFMA): H[N,128] = X[N,256] @ W1  (bf16 output, RTN) ------------
__global__ __launch_bounds__(256) void gemm1_mfma(const float* __restrict__ X,
                                                  const ushort* __restrict__ WTh,
                                                  const ushort* __restrict__ WTl,
                                                  ushort* __restrict__ HB, int N) {
    __shared__ ushort XH[64 * 64], XL[64 * 64];     // 8 KB each
    __shared__ ushort WH[128 * 64], WL[128 * 64];   // 16 KB each
    int t = threadIdx.x;
    int lane = t & 63, w = t >> 6;
    int m_off = (w >> 1) * 32, n_off = (w & 1) * 64;
    long long row0 = (long long)blockIdx.x * 64;
    f32x4 acc[2][4] = {};
    for (int k0 = 0; k0 < IN_C; k0 += 64) {
        __syncthreads();
        {   // stage X tile: 64 rows x 64 k, fp32 -> hi/lo bf16
            int xr = t >> 4, xc = (t & 15) * 4;
            #pragma unroll
            for (int p = 0; p < 4; ++p) {
                int row = xr + p * 16;
                long long gr = row0 + row;
                float4 v = make_float4(0.f, 0.f, 0.f, 0.f);
                if (gr < N) v = *(const float4*)&X[gr * IN_C + k0 + xc];
                ushort4 h4, l4;
                bf16split(v.x, h4.x, l4.x); bf16split(v.y, h4.y, l4.y);
                bf16split(v.z, h4.z, l4.z); bf16split(v.w, h4.w, l4.w);
                *(ushort4*)lds_addr(XH, row, xc) = h4;
                *(ushort4*)lds_addr(XL, row, xc) = l4;
            }
        }
        {   // stage WT tiles: 128 n x 64 k per plane
            int wn = t >> 3, wk = (t & 7) * 8;
            #pragma unroll
            for (int p = 0; p < 4; ++p) {
                int n = wn + p * 32;
                *(short8*)lds_addr(WH, n, wk) = *(const short8*)&WTh[n * IN_C + k0 + wk];
                *(short8*)lds_addr(WL, n, wk) = *(const short8*)&WTl[n * IN_C + k0 + wk];
            }
        }
        __syncthreads();
        #pragma unroll
        for (int kk = 0; kk < 2; ++kk) {
            int ke = kk * 32 + (lane >> 4) * 8;
            short8 ah[2], al[2], bh[4], bl[4];
            #pragma unroll
            for (int mi = 0; mi < 2; ++mi) {
                int r = m_off + mi * 16 + (lane & 15);
                ah[mi] = *(short8*)lds_addr(XH, r, ke);
                al[mi] = *(short8*)lds_addr(XL, r, ke);
            }
            #pragma unroll
            for (int ni = 0; ni < 4; ++ni) {
                int r = n_off + ni * 16 + (lane & 15);
                bh[ni] = *(short8*)lds_addr(WH, r, ke);
                bl[ni] = *(short8*)lds_addr(WL, r, ke);
            }
            #pragma unroll
            for (int mi = 0; mi < 2; ++mi)
                #pragma unroll
                for (int ni = 0; ni < 4; ++ni) {
                    acc[mi][ni] = __builtin_amdgcn_mfma_f32_16x16x32_bf16(ah[mi], bh[ni], acc[mi][ni], 0, 0, 0);
                    acc[mi][ni] = __builtin_amdgcn_mfma_f32_16x16x32_bf16(ah[mi], bl[ni], acc[mi][ni], 0, 0, 0);
                    acc[mi][ni] = __builtin_amdgcn_mfma_f32_16x16x32_bf16(al[mi], bh[ni], acc[mi][ni], 0, 0, 0);
                }
        }
    }
    int cr = (lane >> 4) * 4, cc = lane & 15;
    #pragma unroll
    for (int mi = 0; mi < 2; ++mi)
        #pragma unroll
        for (int j = 0; j < 4; ++j) {
            long long gr = row0 + m_off + mi * 16 + cr + j;
            if (gr < N)
                #pragma unroll
                for (int ni = 0; ni < 4; ++ni)
                    HB[gr * HID + n_off + ni * 16 + cc] = f2bf(acc[mi][ni][j]);
        }
}

// ---- GEMM2 (MFMA): H2[N,64] = relu(AG1[N,128]+b1) @ W2 (bf16 out) ----------
__global__ __launch_bounds__(256) void gemm2_mfma(const float* __restrict__ A,
                                                  const float* __restrict__ b1,
                                                  const ushort* __restrict__ WTh,
                                                  const ushort* __restrict__ WTl,
                                                  ushort* __restrict__ HB, int N) {
    __shared__ ushort AH[64 * 64], AL[64 * 64];
    __shared__ ushort WH[64 * 64], WL[64 * 64];
    int t = threadIdx.x;
    int lane = t & 63, w = t >> 6;
    int m_off = (w >> 1) * 32, n_off = (w & 1) * 32;
    long long row0 = (long long)blockIdx.x * 64;
    f32x4 acc[2][2] = {};
    for (int k0 = 0; k0 < HID; k0 += 64) {
        __syncthreads();
        {   // stage A tile with fused +b1, relu, hi/lo split
            int xr = t >> 4, xc = (t & 15) * 4;
            float4 bb = *(const float4*)&b1[k0 + xc];
            #pragma unroll
            for (int p = 0; p < 4; ++p) {
                int row = xr + p * 16;
                long long gr = row0 + row;
                float4 v = make_float4(0.f, 0.f, 0.f, 0.f);
                if (gr < N) {
                    v = *(const float4*)&A[gr * HID + k0 + xc];
                    v.x = fmaxf(v.x + bb.x, 0.f); v.y = fmaxf(v.y + bb.y, 0.f);
                    v.z = fmaxf(v.z + bb.z, 0.f); v.w = fmaxf(v.w + bb.w, 0.f);
                }
                ushort4 h4, l4;
                bf16split(v.x, h4.x, l4.x); bf16split(v.y, h4.y, l4.y);
                bf16split(v.z, h4.z, l4.z); bf16split(v.w, h4.w, l4.w);
                *(ushort4*)lds_addr(AH, row, xc) = h4;
                *(ushort4*)lds_addr(AL, row, xc) = l4;
            }
        }
        {   // stage W2T tiles: 64 n x 64 k per plane
            int wn = t >> 3, wk = (t & 7) * 8;
            #pragma unroll
            for (int p = 0; p < 2; ++p) {
                int n = wn + p * 32;
                *(short8*)lds_addr(WH, n, wk) = *(const short8*)&WTh[n * HID + k0 + wk];
                *(short8*)lds_addr(WL, n, wk) = *(const short8*)&WTl[n * HID + k0 + wk];
            }
        }
        __syncthreads();
        #pragma unroll
        for (int kk = 0; kk < 2; ++kk) {
            int ke = kk * 32 + (lane >> 4) * 8;
            short8 ah[2], al[2], bh[2], bl[2];
            #pragma unroll
            for (int mi = 0; mi < 2; ++mi) {
                int r = m_off + mi * 16 + (lane & 15);
                ah[mi] = *(short8*)lds_addr(AH, r, ke);
                al[mi] = *(short8*)lds_addr(AL, r, ke);
            }
            #pragma unroll
            for (int ni = 0; ni < 2; ++ni) {
                int r = n_off + ni * 16 + (lane & 15);
                bh[ni] = *(short8*)lds_addr(WH, r, ke);
                bl[ni] = *(short8*)lds_addr(WL, r, ke);
            }
            #pragma unroll
            for (int mi = 0; mi < 2; ++mi)
                #pragma unroll
                for (int ni = 0; ni < 2; ++ni) {
                    acc[mi][ni] = __builtin_amdgcn_mfma_f32_16x16x32_bf16(ah[mi], bh[ni], acc[mi][ni], 0, 0, 0);
                    acc[mi][ni] = __builtin_amdgcn_mfma_f32_16x16x32_bf16(ah[mi], bl[ni], acc[mi][ni], 0, 0, 0);
                    acc[mi][ni] = __builtin_amdgcn_mfma_f32_16x16x32_bf16(al[mi], bh[ni], acc[mi][ni], 0, 0, 0);
                }
        }
    }
    int cr = (lane >> 4) * 4, cc = lane & 15;
    #pragma unroll
    for (int mi = 0; mi < 2; ++mi)
        #pragma unroll
        for (int j = 0; j < 4; ++j) {
            long long gr = row0 + m_off + mi * 16 + cr + j;
            if (gr < N)
                #pragma unroll
                for (int ni = 0; ni < 2; ++ni)
                    HB[gr * OUTC + n_off + ni * 16 + cc] = f2bf(acc[mi][ni][j]);
        }
}

// ---- atomic-free segment aggregation over bf16 rows, fp32 accumulate -------
// One wave per dst node. out[n] = sum_edges h[s]*nrm + h[n]*dn^2 (+bias).
template <int F, bool BIAS>
__global__ void seg_agg_bf16(const ushort* __restrict__ HinB,
                             const float* __restrict__ dis,
                             const int* __restrict__ row_ptr,
                             const int* __restrict__ sorted_src,
                             const float* __restrict__ snrm,
                             const float* __restrict__ bias,
                             float* __restrict__ out, int N) {
    constexpr int PER = F / 64;
    long long wid = ((long long)blockIdx.x * blockDim.x + threadIdx.x) >> 6;
    int lane = threadIdx.x & 63;
    if (wid >= N) return;
    int n = (int)wid;
    float dn = dis[n];
    float a0, a1 = 0.f;
    if constexpr (PER == 2) {
        ushort2 sv = *(const ushort2*)&HinB[(long long)n * F + lane * 2];
        a0 = bf2f(sv.x) * (dn * dn);
        a1 = bf2f(sv.y) * (dn * dn);
    } else {
        a0 = bf2f(HinB[(long long)n * F + lane]) * (dn * dn);
    }
    int e0 = row_ptr[n], e1 = row_ptr[n + 1];
    for (int e = e0; e < e1; ++e) {
        int s = sorted_src[e];
        float nrm = snrm[e];
        if constexpr (PER == 2) {
            ushort2 v = *(const ushort2*)&HinB[(long long)s * F + lane * 2];
            a0 += bf2f(v.x) * nrm;
            a1 += bf2f(v.y) * nrm;
        } else {
            a0 += bf2f(HinB[(long long)s * F + lane]) * nrm;
        }
    }
    if constexpr (PER == 2) {
        float2 o;
        o.x = BIAS ? a0 + bias[lane * 2] : a0;
        o.y = BIAS ? a1 + bias[lane * 2 + 1] : a1;
        *(float2*)&out[(long long)n * F + lane * 2] = o;
    } else {
        out[(long long)n * F + lane] = BIAS ? a0 + bias[lane] : a0;
    }
}

extern "C" void kernel_launch(void* const* d_in, const int* in_sizes, int n_in,
                              void* d_out, int out_size, void* d_ws, size_t ws_size,
                              hipStream_t stream) {
    const float* x  = (const float*)d_in[0];
    const void*  ei = d_in[1];
    const float* W1 = (const float*)d_in[2];
    const float* b1 = (const float*)d_in[3];
    const float* W2 = (const float*)d_in[4];
    const float* b2 = (const float*)d_in[5];
    float* out = (float*)d_out;
    int N = in_sizes[0] / IN_C;    // 50000
    int E = in_sizes[1] / 2;       // 800000

    char* ws = (char*)d_ws;
    size_t off = 0;
    auto alloc = [&](size_t bytes) {
        void* p = ws + off;
        off += ((bytes + 255) / 256) * 256;
        return p;
    };
    int nb = (N + SCAN_BLK - 1) / SCAN_BLK;  // 196
    int*    flag       = (int*)alloc(4);
    int*    degi       = (int*)alloc((size_t)N * 4);
    int*    bsum       = (int*)alloc((size_t)nb * 4);
    int*    row_ptr    = (int*)alloc(((size_t)N + 1) * 4);
    int*    cursor     = (int*)alloc((size_t)N * 4);
    float*  dis        = (float*)alloc((size_t)N * 4);
    int*    sorted_src = (int*)alloc((size_t)E * 4);
    float*  snrm       = (float*)alloc((size_t)E * 4);
    ushort* w1h        = (ushort*)alloc((size_t)HID * IN_C * 2);
    ushort* w1l        = (ushort*)alloc((size_t)HID * IN_C * 2);
    ushort* w2h        = (ushort*)alloc((size_t)OUTC * HID * 2);
    ushort* w2l        = (ushort*)alloc((size_t)OUTC * HID * 2);
    ushort* H1b        = (ushort*)alloc((size_t)N * HID * 2);
    float*  AG1        = (float*)alloc((size_t)N * HID * 4);
    ushort* H2b        = (ushort*)alloc((size_t)N * OUTC * 2);

    hipMemsetAsync(degi, 0, (size_t)N * 4, stream);

    detect_kernel<<<1, 64, 0, stream>>>((const unsigned long long*)ei, flag);
    wtrans_kernel<<<(HID * IN_C + 255) / 256, 256, 0, stream>>>(W1, W2, w1h, w1l, w2h, w2l);
    degi_kernel<<<1024, 256, 0, stream>>>(ei, flag, degi, E);
    scan_sums_kernel<<<nb, SCAN_BLK, 0, stream>>>(degi, bsum, N);
    scan_bsum_kernel<<<1, SCAN_BLK, 0, stream>>>(bsum, nb);
    scan_emit_kernel<<<nb, SCAN_BLK, 0, stream>>>(degi, bsum, row_ptr, cursor, dis, N);
    scatter_kernel<<<1024, 256, 0, stream>>>(ei, flag, dis, cursor, sorted_src, snrm, E);
    gemm1_mfma<<<(N + 63) / 64, 256, 0, stream>>>(x, w1h, w1l, H1b, N);
    seg_agg_bf16<HID, false><<<((long long)N * 64 + 255) / 256, 256, 0, stream>>>(
        H1b, dis, row_ptr, sorted_src, snrm, nullptr, AG1, N);
    gemm2_mfma<<<(N + 63) / 64, 256, 0, stream>>>(AG1, b1, w2h, w2l, H2b, N);
    seg_agg_bf16<OUTC, true><<<((long long)N * 64 + 255) / 256, 256, 0, stream>>>(
        H2b, dis, row_ptr, sorted_src, snrm, b2, out, N);
}

// Round 6
// 248.751 us; speedup vs baseline: 2.8282x; 1.1415x over previous
//
#include <hip/hip_runtime.h>

// GCN 2-layer encoder: N=50000 nodes, E=800000 edges, 256 -> 128 -> 64.
// Round 6: seg_agg was latency-bound (same 81us for F=128 and F=64).
// 8-deep software-pipelined gathers + packed (src,norm) edge records.

#define IN_C 256
#define HID 128
#define OUTC 64
#define SCAN_BLK 256

typedef __attribute__((ext_vector_type(8))) short short8;
typedef __attribute__((ext_vector_type(4))) float f32x4;

// ---- fp32 -> bf16 hi/lo split (exact to ~2^-17 rel) ------------------------
__device__ __forceinline__ void bf16split(float f, ushort& h, ushort& l) {
    unsigned u = __float_as_uint(f);
    h = (ushort)(u >> 16);
    float hf = __uint_as_float(u & 0xFFFF0000u);
    unsigned v = __float_as_uint(f - hf);
    l = (ushort)((v + 0x7FFF + ((v >> 16) & 1)) >> 16);
}

// fp32 -> bf16 round-to-nearest-even
__device__ __forceinline__ ushort f2bf(float f) {
    unsigned u = __float_as_uint(f);
    return (ushort)((u + 0x7FFF + ((u >> 16) & 1)) >> 16);
}
__device__ __forceinline__ float bf2f(ushort u) {
    return __uint_as_float((unsigned)u << 16);
}

// ---- swizzled LDS addressing for [row][64 k] bf16 tiles (128 B rows) -------
__device__ __forceinline__ void* lds_addr(void* base, int row, int kelem) {
    int byte = row * 128 + kelem * 2;
    byte ^= (row & 7) << 4;
    return (char*)base + byte;
}

// ---- edge index access (int64 vs int32 detected at runtime) ----------------
__device__ __forceinline__ int edge_at(const void* ei, long long idx, int is32) {
    return is32 ? ((const int*)ei)[idx] : (int)((const long long*)ei)[idx];
}

__global__ void detect_kernel(const unsigned long long* ei, int* flag) {
    if (threadIdx.x == 0 && blockIdx.x == 0) {
        int is32 = 0;
        for (int i = 0; i < 64; ++i)
            if (ei[i] >> 32) { is32 = 1; break; }
        *flag = is32;
    }
}

// ---- weight pre-transpose + split: W[k][n] -> WT_hi/lo[n][k] ---------------
__global__ void wtrans_kernel(const float* __restrict__ W1, const float* __restrict__ W2,
                              ushort* __restrict__ w1h, ushort* __restrict__ w1l,
                              ushort* __restrict__ w2h, ushort* __restrict__ w2l) {
    int id = blockIdx.x * blockDim.x + threadIdx.x;
    if (id < HID * IN_C) {                     // 128 n x 256 k
        int n = id >> 8, k = id & 255;
        ushort h, l; bf16split(W1[k * HID + n], h, l);
        w1h[id] = h; w1l[id] = l;
    }
    if (id < OUTC * HID) {                     // 64 n x 128 k
        int n = id >> 7, k = id & 127;
        ushort h, l; bf16split(W2[k * OUTC + n], h, l);
        w2h[id] = h; w2l[id] = l;
    }
}

// ---- integer degree histogram over dst -------------------------------------
__global__ void degi_kernel(const void* ei, const int* __restrict__ flag,
                            int* __restrict__ degi, int E) {
    int is32 = *flag;
    long long stride = (long long)gridDim.x * blockDim.x;
    for (long long e = (long long)blockIdx.x * blockDim.x + threadIdx.x; e < E; e += stride) {
        int d = edge_at(ei, (long long)E + e, is32);
        atomicAdd(&degi[d], 1);
    }
}

// ---- hierarchical exclusive scan -------------------------------------------
__global__ __launch_bounds__(SCAN_BLK) void scan_sums_kernel(const int* __restrict__ degi,
                                                             int* __restrict__ bsum, int N) {
    int i = blockIdx.x * SCAN_BLK + threadIdx.x;
    int v = (i < N) ? degi[i] : 0;
    #pragma unroll
    for (int d = 32; d > 0; d >>= 1) v += __shfl_down(v, d, 64);
    __shared__ int ws[4];
    if ((threadIdx.x & 63) == 0) ws[threadIdx.x >> 6] = v;
    __syncthreads();
    if (threadIdx.x == 0) bsum[blockIdx.x] = ws[0] + ws[1] + ws[2] + ws[3];
}

__global__ __launch_bounds__(SCAN_BLK) void scan_bsum_kernel(int* __restrict__ bsum, int nb) {
    __shared__ int sh[SCAN_BLK];
    int t = threadIdx.x;
    int v = (t < nb) ? bsum[t] : 0;
    sh[t] = v;
    __syncthreads();
    #pragma unroll
    for (int d = 1; d < SCAN_BLK; d <<= 1) {
        int add = (t >= d) ? sh[t - d] : 0;
        __syncthreads();
        sh[t] += add;
        __syncthreads();
    }
    if (t < nb) bsum[t] = sh[t] - v;  // exclusive
}

__global__ __launch_bounds__(SCAN_BLK) void scan_emit_kernel(const int* __restrict__ degi,
                                                             const int* __restrict__ bsum,
                                                             int* __restrict__ row_ptr,
                                                             int* __restrict__ cursor,
                                                             float* __restrict__ dis, int N) {
    __shared__ int sh[SCAN_BLK];
    int t = threadIdx.x;
    int i = blockIdx.x * SCAN_BLK + t;
    int v = (i < N) ? degi[i] : 0;
    sh[t] = v;
    __syncthreads();
    #pragma unroll
    for (int d = 1; d < SCAN_BLK; d <<= 1) {
        int add = (t >= d) ? sh[t - d] : 0;
        __syncthreads();
        sh[t] += add;
        __syncthreads();
    }
    if (i < N) {
        int excl = bsum[blockIdx.x] + sh[t] - v;
        row_ptr[i] = excl;
        cursor[i] = excl;
        dis[i] = rsqrtf((float)v + 1.0f);  // +1 = self loop
        if (i == N - 1) row_ptr[N] = excl + v;  // = E
    }
}

// ---- scatter packed (src, norm) edge records into dst-sorted order ---------
__global__ void scatter_kernel(const void* ei, const int* __restrict__ flag,
                               const float* __restrict__ dis,
                               int* __restrict__ cursor, int2* __restrict__ epk, int E) {
    int is32 = *flag;
    long long stride = (long long)gridDim.x * blockDim.x;
    for (long long e = (long long)blockIdx.x * blockDim.x + threadIdx.x; e < E; e += stride) {
        int s = edge_at(ei, e, is32);
        int d = edge_at(ei, (long long)E + e, is32);
        int pos = atomicAdd(&cursor[d], 1);
        epk[pos] = make_int2(s, __float_as_int(dis[s] * dis[d]));
    }
}

// ---- GEMM1 (MFMA): H[N,128] = X[N,256] @ W1  (bf16 output, RTN) ------------
__global__ __launch_bounds__(256) void gemm1_mfma(const float* __restrict__ X,
                                                  const ushort* __restrict__ WTh,
                                                  const ushort* __restrict__ WTl,
                                                  ushort* __restrict__ HB, int N) {
    __shared__ ushort XH[64 * 64], XL[64 * 64];     // 8 KB each
    __shared__ ushort WH[128 * 64], WL[128 * 64];   // 16 KB each
    int t = threadIdx.x;
    int lane = t & 63, w = t >> 6;
    int m_off = (w >> 1) * 32, n_off = (w & 1) * 64;
    long long row0 = (long long)blockIdx.x * 64;
    f32x4 acc[2][4] = {};
    for (int k0 = 0; k0 < IN_C; k0 += 64) {
        __syncthreads();
        {   // stage X tile: 64 rows x 64 k, fp32 -> hi/lo bf16
            int xr = t >> 4, xc = (t & 15) * 4;
            #pragma unroll
            for (int p = 0; p < 4; ++p) {
                int row = xr + p * 16;
                long long gr = row0 + row;
                float4 v = make_float4(0.f, 0.f, 0.f, 0.f);
                if (gr < N) v = *(const float4*)&X[gr * IN_C + k0 + xc];
                ushort4 h4, l4;
                bf16split(v.x, h4.x, l4.x); bf16split(v.y, h4.y, l4.y);
                bf16split(v.z, h4.z, l4.z); bf16split(v.w, h4.w, l4.w);
                *(ushort4*)lds_addr(XH, row, xc) = h4;
                *(ushort4*)lds_addr(XL, row, xc) = l4;
            }
        }
        {   // stage WT tiles: 128 n x 64 k per plane
            int wn = t >> 3, wk = (t & 7) * 8;
            #pragma unroll
            for (int p = 0; p < 4; ++p) {
                int n = wn + p * 32;
                *(short8*)lds_addr(WH, n, wk) = *(const short8*)&WTh[n * IN_C + k0 + wk];
                *(short8*)lds_addr(WL, n, wk) = *(const short8*)&WTl[n * IN_C + k0 + wk];
            }
        }
        __syncthreads();
        #pragma unroll
        for (int kk = 0; kk < 2; ++kk) {
            int ke = kk * 32 + (lane >> 4) * 8;
            short8 ah[2], al[2], bh[4], bl[4];
            #pragma unroll
            for (int mi = 0; mi < 2; ++mi) {
                int r = m_off + mi * 16 + (lane & 15);
                ah[mi] = *(short8*)lds_addr(XH, r, ke);
                al[mi] = *(short8*)lds_addr(XL, r, ke);
            }
            #pragma unroll
            for (int ni = 0; ni < 4; ++ni) {
                int r = n_off + ni * 16 + (lane & 15);
                bh[ni] = *(short8*)lds_addr(WH, r, ke);
                bl[ni] = *(short8*)lds_addr(WL, r, ke);
            }
            #pragma unroll
            for (int mi = 0; mi < 2; ++mi)
                #pragma unroll
                for (int ni = 0; ni < 4; ++ni) {
                    acc[mi][ni] = __builtin_amdgcn_mfma_f32_16x16x32_bf16(ah[mi], bh[ni], acc[mi][ni], 0, 0, 0);
                    acc[mi][ni] = __builtin_amdgcn_mfma_f32_16x16x32_bf16(ah[mi], bl[ni], acc[mi][ni], 0, 0, 0);
                    acc[mi][ni] = __builtin_amdgcn_mfma_f32_16x16x32_bf16(al[mi], bh[ni], acc[mi][ni], 0, 0, 0);
                }
        }
    }
    int cr = (lane >> 4) * 4, cc = lane & 15;
    #pragma unroll
    for (int mi = 0; mi < 2; ++mi)
        #pragma unroll
        for (int j = 0; j < 4; ++j) {
            long long gr = row0 + m_off + mi * 16 + cr + j;
            if (gr < N)
                #pragma unroll
                for (int ni = 0; ni < 4; ++ni)
                    HB[gr * HID + n_off + ni * 16 + cc] = f2bf(acc[mi][ni][j]);
        }
}

// ---- GEMM2 (MFMA): H2[N,64] = relu(AG1[N,128]+b1) @ W2 (bf16 out) ----------
__global__ __launch_bounds__(256) void gemm2_mfma(const float* __restrict__ A,
                                                  const float* __restrict__ b1,
                                                  const ushort* __restrict__ WTh,
                                                  const ushort* __restrict__ WTl,
                                                  ushort* __restrict__ HB, int N) {
    __shared__ ushort AH[64 * 64], AL[64 * 64];
    __shared__ ushort WH[64 * 64], WL[64 * 64];
    int t = threadIdx.x;
    int lane = t & 63, w = t >> 6;
    int m_off = (w >> 1) * 32, n_off = (w & 1) * 32;
    long long row0 = (long long)blockIdx.x * 64;
    f32x4 acc[2][2] = {};
    for (int k0 = 0; k0 < HID; k0 += 64) {
        __syncthreads();
        {   // stage A tile with fused +b1, relu, hi/lo split
            int xr = t >> 4, xc = (t & 15) * 4;
            float4 bb = *(const float4*)&b1[k0 + xc];
            #pragma unroll
            for (int p = 0; p < 4; ++p) {
                int row = xr + p * 16;
                long long gr = row0 + row;
                float4 v = make_float4(0.f, 0.f, 0.f, 0.f);
                if (gr < N) {
                    v = *(const float4*)&A[gr * HID + k0 + xc];
                    v.x = fmaxf(v.x + bb.x, 0.f); v.y = fmaxf(v.y + bb.y, 0.f);
                    v.z = fmaxf(v.z + bb.z, 0.f); v.w = fmaxf(v.w + bb.w, 0.f);
                }
                ushort4 h4, l4;
                bf16split(v.x, h4.x, l4.x); bf16split(v.y, h4.y, l4.y);
                bf16split(v.z, h4.z, l4.z); bf16split(v.w, h4.w, l4.w);
                *(ushort4*)lds_addr(AH, row, xc) = h4;
                *(ushort4*)lds_addr(AL, row, xc) = l4;
            }
        }
        {   // stage W2T tiles: 64 n x 64 k per plane
            int wn = t >> 3, wk = (t & 7) * 8;
            #pragma unroll
            for (int p = 0; p < 2; ++p) {
                int n = wn + p * 32;
                *(short8*)lds_addr(WH, n, wk) = *(const short8*)&WTh[n * HID + k0 + wk];
                *(short8*)lds_addr(WL, n, wk) = *(const short8*)&WTl[n * HID + k0 + wk];
            }
        }
        __syncthreads();
        #pragma unroll
        for (int kk = 0; kk < 2; ++kk) {
            int ke = kk * 32 + (lane >> 4) * 8;
            short8 ah[2], al[2], bh[2], bl[2];
            #pragma unroll
            for (int mi = 0; mi < 2; ++mi) {
                int r = m_off + mi * 16 + (lane & 15);
                ah[mi] = *(short8*)lds_addr(AH, r, ke);
                al[mi] = *(short8*)lds_addr(AL, r, ke);
            }
            #pragma unroll
            for (int ni = 0; ni < 2; ++ni) {
                int r = n_off + ni * 16 + (lane & 15);
                bh[ni] = *(short8*)lds_addr(WH, r, ke);
                bl[ni] = *(short8*)lds_addr(WL, r, ke);
            }
            #pragma unroll
            for (int mi = 0; mi < 2; ++mi)
                #pragma unroll
                for (int ni = 0; ni < 2; ++ni) {
                    acc[mi][ni] = __builtin_amdgcn_mfma_f32_16x16x32_bf16(ah[mi], bh[ni], acc[mi][ni], 0, 0, 0);
                    acc[mi][ni] = __builtin_amdgcn_mfma_f32_16x16x32_bf16(ah[mi], bl[ni], acc[mi][ni], 0, 0, 0);
                    acc[mi][ni] = __builtin_amdgcn_mfma_f32_16x16x32_bf16(al[mi], bh[ni], acc[mi][ni], 0, 0, 0);
                }
        }
    }
    int cr = (lane >> 4) * 4, cc = lane & 15;
    #pragma unroll
    for (int mi = 0; mi < 2; ++mi)
        #pragma unroll
        for (int j = 0; j < 4; ++j) {
            long long gr = row0 + m_off + mi * 16 + cr + j;
            if (gr < N)
                #pragma unroll
                for (int ni = 0; ni < 2; ++ni)
                    HB[gr * OUTC + n_off + ni * 16 + cc] = f2bf(acc[mi][ni][j]);
        }
}

// ---- segment aggregation, 8-deep pipelined gathers -------------------------
// One wave per dst node; batches of 8 edges with OOB slots clamped to e1-1
// and weight 0, keeping 8 independent row-gathers in flight at all times.
template <int F, bool BIAS>
__global__ void seg_agg_bf16(const ushort* __restrict__ HinB,
                             const float* __restrict__ dis,
                             const int* __restrict__ row_ptr,
                             const int2* __restrict__ epk,
                             const float* __restrict__ bias,
                             float* __restrict__ out, int N) {
    constexpr int PER = F / 64;   // 2 for F=128, 1 for F=64
    int wid = (int)(((long long)blockIdx.x * blockDim.x + threadIdx.x) >> 6);
    int lane = threadIdx.x & 63;
    if (wid >= N) return;
    int n = wid;
    float dn = dis[n];
    float a0, a1 = 0.f;
    {   // self loop
        unsigned boff = (unsigned)n * F + lane * PER;
        if constexpr (PER == 2) {
            unsigned hv = *(const unsigned*)&HinB[boff];
            a0 = bf2f((ushort)hv) * (dn * dn);
            a1 = bf2f((ushort)(hv >> 16)) * (dn * dn);
        } else {
            a0 = bf2f(HinB[boff]) * (dn * dn);
        }
    }
    int e0 = row_ptr[n], e1 = row_ptr[n + 1];
    for (int e = e0; e < e1; e += 8) {
        unsigned hv[8]; float nr[8];
        #pragma unroll
        for (int u = 0; u < 8; ++u) {
            int idx = (e + u < e1) ? e + u : e1 - 1;
            int2 p = epk[idx];
            nr[u] = (e + u < e1) ? __int_as_float(p.y) : 0.0f;
            unsigned boff = (unsigned)p.x * F + lane * PER;
            if constexpr (PER == 2) hv[u] = *(const unsigned*)&HinB[boff];
            else                    hv[u] = HinB[boff];
        }
        #pragma unroll
        for (int u = 0; u < 8; ++u) {
            if constexpr (PER == 2) {
                a0 += bf2f((ushort)hv[u]) * nr[u];
                a1 += bf2f((ushort)(hv[u] >> 16)) * nr[u];
            } else {
                a0 += bf2f((ushort)hv[u]) * nr[u];
            }
        }
    }
    unsigned obase = (unsigned)n * F + lane * PER;
    if constexpr (PER == 2) {
        float2 o;
        o.x = BIAS ? a0 + bias[lane * 2] : a0;
        o.y = BIAS ? a1 + bias[lane * 2 + 1] : a1;
        *(float2*)&out[obase] = o;
    } else {
        out[obase] = BIAS ? a0 + bias[lane] : a0;
    }
}

extern "C" void kernel_launch(void* const* d_in, const int* in_sizes, int n_in,
                              void* d_out, int out_size, void* d_ws, size_t ws_size,
                              hipStream_t stream) {
    const float* x  = (const float*)d_in[0];
    const void*  ei = d_in[1];
    const float* W1 = (const float*)d_in[2];
    const float* b1 = (const float*)d_in[3];
    const float* W2 = (const float*)d_in[4];
    const float* b2 = (const float*)d_in[5];
    float* out = (float*)d_out;
    int N = in_sizes[0] / IN_C;    // 50000
    int E = in_sizes[1] / 2;       // 800000

    char* ws = (char*)d_ws;
    size_t off = 0;
    auto alloc = [&](size_t bytes) {
        void* p = ws + off;
        off += ((bytes + 255) / 256) * 256;
        return p;
    };
    int nb = (N + SCAN_BLK - 1) / SCAN_BLK;  // 196
    int*    flag       = (int*)alloc(4);
    int*    degi       = (int*)alloc((size_t)N * 4);
    int*    bsum       = (int*)alloc((size_t)nb * 4);
    int*    row_ptr    = (int*)alloc(((size_t)N + 1) * 4);
    int*    cursor     = (int*)alloc((size_t)N * 4);
    float*  dis        = (float*)alloc((size_t)N * 4);
    int2*   epk        = (int2*)alloc((size_t)E * 8);
    ushort* w1h        = (ushort*)alloc((size_t)HID * IN_C * 2);
    ushort* w1l        = (ushort*)alloc((size_t)HID * IN_C * 2);
    ushort* w2h        = (ushort*)alloc((size_t)OUTC * HID * 2);
    ushort* w2l        = (ushort*)alloc((size_t)OUTC * HID * 2);
    ushort* H1b        = (ushort*)alloc((size_t)N * HID * 2);
    float*  AG1        = (float*)alloc((size_t)N * HID * 4);
    ushort* H2b        = (ushort*)alloc((size_t)N * OUTC * 2);

    hipMemsetAsync(degi, 0, (size_t)N * 4, stream);

    detect_kernel<<<1, 64, 0, stream>>>((const unsigned long long*)ei, flag);
    wtrans_kernel<<<(HID * IN_C + 255) / 256, 256, 0, stream>>>(W1, W2, w1h, w1l, w2h, w2l);
    degi_kernel<<<1024, 256, 0, stream>>>(ei, flag, degi, E);
    scan_sums_kernel<<<nb, SCAN_BLK, 0, stream>>>(degi, bsum, N);
    scan_bsum_kernel<<<1, SCAN_BLK, 0, stream>>>(bsum, nb);
    scan_emit_kernel<<<nb, SCAN_BLK, 0, stream>>>(degi, bsum, row_ptr, cursor, dis, N);
    scatter_kernel<<<1024, 256, 0, stream>>>(ei, flag, dis, cursor, epk, E);
    gemm1_mfma<<<(N + 63) / 64, 256, 0, stream>>>(x, w1h, w1l, H1b, N);
    seg_agg_bf16<HID, false><<<((long long)N * 64 + 255) / 256, 256, 0, stream>>>(
        H1b, dis, row_ptr, epk, nullptr, AG1, N);
    gemm2_mfma<<<(N + 63) / 64, 256, 0, stream>>>(AG1, b1, w2h, w2l, H2b, N);
    seg_agg_bf16<OUTC, true><<<((long long)N * 64 + 255) / 256, 256, 0, stream>>>(
        H2b, dis, row_ptr, epk, b2, out, N);
}

// Round 7
// 213.166 us; speedup vs baseline: 3.3003x; 1.1669x over previous
//
#include <hip/hip_runtime.h>

// GCN 2-layer encoder: N=50000 nodes, E=800000 edges, 256 -> 128 -> 64.
// Round 7: seg_agg restructured — wave-coalesced edge-record loads +
// readlane broadcast (src/norm in SGPRs), 16-deep gather pipeline,
// F=128 split across 2 waves/node for 2x concurrency.

#define IN_C 256
#define HID 128
#define OUTC 64
#define SCAN_BLK 256

typedef __attribute__((ext_vector_type(8))) short short8;
typedef __attribute__((ext_vector_type(4))) float f32x4;

// ---- fp32 -> bf16 hi/lo split (exact to ~2^-17 rel) ------------------------
__device__ __forceinline__ void bf16split(float f, ushort& h, ushort& l) {
    unsigned u = __float_as_uint(f);
    h = (ushort)(u >> 16);
    float hf = __uint_as_float(u & 0xFFFF0000u);
    unsigned v = __float_as_uint(f - hf);
    l = (ushort)((v + 0x7FFF + ((v >> 16) & 1)) >> 16);
}

// fp32 -> bf16 round-to-nearest-even
__device__ __forceinline__ ushort f2bf(float f) {
    unsigned u = __float_as_uint(f);
    return (ushort)((u + 0x7FFF + ((u >> 16) & 1)) >> 16);
}
__device__ __forceinline__ float bf2f(ushort u) {
    return __uint_as_float((unsigned)u << 16);
}

// ---- swizzled LDS addressing for [row][64 k] bf16 tiles (128 B rows) -------
__device__ __forceinline__ void* lds_addr(void* base, int row, int kelem) {
    int byte = row * 128 + kelem * 2;
    byte ^= (row & 7) << 4;
    return (char*)base + byte;
}

// ---- edge index access (int64 vs int32 detected at runtime) ----------------
__device__ __forceinline__ int edge_at(const void* ei, long long idx, int is32) {
    return is32 ? ((const int*)ei)[idx] : (int)((const long long*)ei)[idx];
}

__global__ void detect_kernel(const unsigned long long* ei, int* flag) {
    if (threadIdx.x == 0 && blockIdx.x == 0) {
        int is32 = 0;
        for (int i = 0; i < 64; ++i)
            if (ei[i] >> 32) { is32 = 1; break; }
        *flag = is32;
    }
}

// ---- weight pre-transpose + split: W[k][n] -> WT_hi/lo[n][k] ---------------
__global__ void wtrans_kernel(const float* __restrict__ W1, const float* __restrict__ W2,
                              ushort* __restrict__ w1h, ushort* __restrict__ w1l,
                              ushort* __restrict__ w2h, ushort* __restrict__ w2l) {
    int id = blockIdx.x * blockDim.x + threadIdx.x;
    if (id < HID * IN_C) {                     // 128 n x 256 k
        int n = id >> 8, k = id & 255;
        ushort h, l; bf16split(W1[k * HID + n], h, l);
        w1h[id] = h; w1l[id] = l;
    }
    if (id < OUTC * HID) {                     // 64 n x 128 k
        int n = id >> 7, k = id & 127;
        ushort h, l; bf16split(W2[k * OUTC + n], h, l);
        w2h[id] = h; w2l[id] = l;
    }
}

// ---- integer degree histogram over dst -------------------------------------
__global__ void degi_kernel(const void* ei, const int* __restrict__ flag,
                            int* __restrict__ degi, int E) {
    int is32 = *flag;
    long long stride = (long long)gridDim.x * blockDim.x;
    for (long long e = (long long)blockIdx.x * blockDim.x + threadIdx.x; e < E; e += stride) {
        int d = edge_at(ei, (long long)E + e, is32);
        atomicAdd(&degi[d], 1);
    }
}

// ---- hierarchical exclusive scan -------------------------------------------
__global__ __launch_bounds__(SCAN_BLK) void scan_sums_kernel(const int* __restrict__ degi,
                                                             int* __restrict__ bsum, int N) {
    int i = blockIdx.x * SCAN_BLK + threadIdx.x;
    int v = (i < N) ? degi[i] : 0;
    #pragma unroll
    for (int d = 32; d > 0; d >>= 1) v += __shfl_down(v, d, 64);
    __shared__ int ws[4];
    if ((threadIdx.x & 63) == 0) ws[threadIdx.x >> 6] = v;
    __syncthreads();
    if (threadIdx.x == 0) bsum[blockIdx.x] = ws[0] + ws[1] + ws[2] + ws[3];
}

__global__ __launch_bounds__(SCAN_BLK) void scan_bsum_kernel(int* __restrict__ bsum, int nb) {
    __shared__ int sh[SCAN_BLK];
    int t = threadIdx.x;
    int v = (t < nb) ? bsum[t] : 0;
    sh[t] = v;
    __syncthreads();
    #pragma unroll
    for (int d = 1; d < SCAN_BLK; d <<= 1) {
        int add = (t >= d) ? sh[t - d] : 0;
        __syncthreads();
        sh[t] += add;
        __syncthreads();
    }
    if (t < nb) bsum[t] = sh[t] - v;  // exclusive
}

__global__ __launch_bounds__(SCAN_BLK) void scan_emit_kernel(const int* __restrict__ degi,
                                                             const int* __restrict__ bsum,
                                                             int* __restrict__ row_ptr,
                                                             int* __restrict__ cursor,
                                                             float* __restrict__ dis, int N) {
    __shared__ int sh[SCAN_BLK];
    int t = threadIdx.x;
    int i = blockIdx.x * SCAN_BLK + t;
    int v = (i < N) ? degi[i] : 0;
    sh[t] = v;
    __syncthreads();
    #pragma unroll
    for (int d = 1; d < SCAN_BLK; d <<= 1) {
        int add = (t >= d) ? sh[t - d] : 0;
        __syncthreads();
        sh[t] += add;
        __syncthreads();
    }
    if (i < N) {
        int excl = bsum[blockIdx.x] + sh[t] - v;
        row_ptr[i] = excl;
        cursor[i] = excl;
        dis[i] = rsqrtf((float)v + 1.0f);  // +1 = self loop
        if (i == N - 1) row_ptr[N] = excl + v;  // = E
    }
}

// ---- scatter packed (src, norm) edge records into dst-sorted order ---------
__global__ void scatter_kernel(const void* ei, const int* __restrict__ flag,
                               const float* __restrict__ dis,
                               int* __restrict__ cursor, int2* __restrict__ epk, int E) {
    int is32 = *flag;
    long long stride = (long long)gridDim.x * blockDim.x;
    for (long long e = (long long)blockIdx.x * blockDim.x + threadIdx.x; e < E; e += stride) {
        int s = edge_at(ei, e, is32);
        int d = edge_at(ei, (long long)E + e, is32);
        int pos = atomicAdd(&cursor[d], 1);
        epk[pos] = make_int2(s, __float_as_int(dis[s] * dis[d]));
    }
}

// ---- GEMM1 (MFMA): H[N,128] = X[N,256] @ W1  (bf16 output, RTN) ------------
__global__ __launch_bounds__(256) void gemm1_mfma(const float* __restrict__ X,
                                                  const ushort* __restrict__ WTh,
                                                  const ushort* __restrict__ WTl,
                                                  ushort* __restrict__ HB, int N) {
    __shared__ ushort XH[64 * 64], XL[64 * 64];     // 8 KB each
    __shared__ ushort WH[128 * 64], WL[128 * 64];   // 16 KB each
    int t = threadIdx.x;
    int lane = t & 63, w = t >> 6;
    int m_off = (w >> 1) * 32, n_off = (w & 1) * 64;
    long long row0 = (long long)blockIdx.x * 64;
    f32x4 acc[2][4] = {};
    for (int k0 = 0; k0 < IN_C; k0 += 64) {
        __syncthreads();
        {   // stage X tile: 64 rows x 64 k, fp32 -> hi/lo bf16
            int xr = t >> 4, xc = (t & 15) * 4;
            #pragma unroll
            for (int p = 0; p < 4; ++p) {
                int row = xr + p * 16;
                long long gr = row0 + row;
                float4 v = make_float4(0.f, 0.f, 0.f, 0.f);
                if (gr < N) v = *(const float4*)&X[gr * IN_C + k0 + xc];
                ushort4 h4, l4;
                bf16split(v.x, h4.x, l4.x); bf16split(v.y, h4.y, l4.y);
                bf16split(v.z, h4.z, l4.z); bf16split(v.w, h4.w, l4.w);
                *(ushort4*)lds_addr(XH, row, xc) = h4;
                *(ushort4*)lds_addr(XL, row, xc) = l4;
            }
        }
        {   // stage WT tiles: 128 n x 64 k per plane
            int wn = t >> 3, wk = (t & 7) * 8;
            #pragma unroll
            for (int p = 0; p < 4; ++p) {
                int n = wn + p * 32;
                *(short8*)lds_addr(WH, n, wk) = *(const short8*)&WTh[n * IN_C + k0 + wk];
                *(short8*)lds_addr(WL, n, wk) = *(const short8*)&WTl[n * IN_C + k0 + wk];
            }
        }
        __syncthreads();
        #pragma unroll
        for (int kk = 0; kk < 2; ++kk) {
            int ke = kk * 32 + (lane >> 4) * 8;
            short8 ah[2], al[2], bh[4], bl[4];
            #pragma unroll
            for (int mi = 0; mi < 2; ++mi) {
                int r = m_off + mi * 16 + (lane & 15);
                ah[mi] = *(short8*)lds_addr(XH, r, ke);
                al[mi] = *(short8*)lds_addr(XL, r, ke);
            }
            #pragma unroll
            for (int ni = 0; ni < 4; ++ni) {
                int r = n_off + ni * 16 + (lane & 15);
                bh[ni] = *(short8*)lds_addr(WH, r, ke);
                bl[ni] = *(short8*)lds_addr(WL, r, ke);
            }
            #pragma unroll
            for (int mi = 0; mi < 2; ++mi)
                #pragma unroll
                for (int ni = 0; ni < 4; ++ni) {
                    acc[mi][ni] = __builtin_amdgcn_mfma_f32_16x16x32_bf16(ah[mi], bh[ni], acc[mi][ni], 0, 0, 0);
                    acc[mi][ni] = __builtin_amdgcn_mfma_f32_16x16x32_bf16(ah[mi], bl[ni], acc[mi][ni], 0, 0, 0);
                    acc[mi][ni] = __builtin_amdgcn_mfma_f32_16x16x32_bf16(al[mi], bh[ni], acc[mi][ni], 0, 0, 0);
                }
        }
    }
    int cr = (lane >> 4) * 4, cc = lane & 15;
    #pragma unroll
    for (int mi = 0; mi < 2; ++mi)
        #pragma unroll
        for (int j = 0; j < 4; ++j) {
            long long gr = row0 + m_off + mi * 16 + cr + j;
            if (gr < N)
                #pragma unroll
                for (int ni = 0; ni < 4; ++ni)
                    HB[gr * HID + n_off + ni * 16 + cc] = f2bf(acc[mi][ni][j]);
        }
}

// ---- GEMM2 (MFMA): H2[N,64] = relu(AG1[N,128]+b1) @ W2 (bf16 out) ----------
__global__ __launch_bounds__(256) void gemm2_mfma(const float* __restrict__ A,
                                                  const float* __restrict__ b1,
                                                  const ushort* __restrict__ WTh,
                                                  const ushort* __restrict__ WTl,
                                                  ushort* __restrict__ HB, int N) {
    __shared__ ushort AH[64 * 64], AL[64 * 64];
    __shared__ ushort WH[64 * 64], WL[64 * 64];
    int t = threadIdx.x;
    int lane = t & 63, w = t >> 6;
    int m_off = (w >> 1) * 32, n_off = (w & 1) * 32;
    long long row0 = (long long)blockIdx.x * 64;
    f32x4 acc[2][2] = {};
    for (int k0 = 0; k0 < HID; k0 += 64) {
        __syncthreads();
        {   // stage A tile with fused +b1, relu, hi/lo split
            int xr = t >> 4, xc = (t & 15) * 4;
            float4 bb = *(const float4*)&b1[k0 + xc];
            #pragma unroll
            for (int p = 0; p < 4; ++p) {
                int row = xr + p * 16;
                long long gr = row0 + row;
                float4 v = make_float4(0.f, 0.f, 0.f, 0.f);
                if (gr < N) {
                    v = *(const float4*)&A[gr * HID + k0 + xc];
                    v.x = fmaxf(v.x + bb.x, 0.f); v.y = fmaxf(v.y + bb.y, 0.f);
                    v.z = fmaxf(v.z + bb.z, 0.f); v.w = fmaxf(v.w + bb.w, 0.f);
                }
                ushort4 h4, l4;
                bf16split(v.x, h4.x, l4.x); bf16split(v.y, h4.y, l4.y);
                bf16split(v.z, h4.z, l4.z); bf16split(v.w, h4.w, l4.w);
                *(ushort4*)lds_addr(AH, row, xc) = h4;
                *(ushort4*)lds_addr(AL, row, xc) = l4;
            }
        }
        {   // stage W2T tiles: 64 n x 64 k per plane
            int wn = t >> 3, wk = (t & 7) * 8;
            #pragma unroll
            for (int p = 0; p < 2; ++p) {
                int n = wn + p * 32;
                *(short8*)lds_addr(WH, n, wk) = *(const short8*)&WTh[n * HID + k0 + wk];
                *(short8*)lds_addr(WL, n, wk) = *(const short8*)&WTl[n * HID + k0 + wk];
            }
        }
        __syncthreads();
        #pragma unroll
        for (int kk = 0; kk < 2; ++kk) {
            int ke = kk * 32 + (lane >> 4) * 8;
            short8 ah[2], al[2], bh[2], bl[2];
            #pragma unroll
            for (int mi = 0; mi < 2; ++mi) {
                int r = m_off + mi * 16 + (lane & 15);
                ah[mi] = *(short8*)lds_addr(AH, r, ke);
                al[mi] = *(short8*)lds_addr(AL, r, ke);
            }
            #pragma unroll
            for (int ni = 0; ni < 2; ++ni) {
                int r = n_off + ni * 16 + (lane & 15);
                bh[ni] = *(short8*)lds_addr(WH, r, ke);
                bl[ni] = *(short8*)lds_addr(WL, r, ke);
            }
            #pragma unroll
            for (int mi = 0; mi < 2; ++mi)
                #pragma unroll
                for (int ni = 0; ni < 2; ++ni) {
                    acc[mi][ni] = __builtin_amdgcn_mfma_f32_16x16x32_bf16(ah[mi], bh[ni], acc[mi][ni], 0, 0, 0);
                    acc[mi][ni] = __builtin_amdgcn_mfma_f32_16x16x32_bf16(ah[mi], bl[ni], acc[mi][ni], 0, 0, 0);
                    acc[mi][ni] = __builtin_amdgcn_mfma_f32_16x16x32_bf16(al[mi], bh[ni], acc[mi][ni], 0, 0, 0);
                }
        }
    }
    int cr = (lane >> 4) * 4, cc = lane & 15;
    #pragma unroll
    for (int mi = 0; mi < 2; ++mi)
        #pragma unroll
        for (int j = 0; j < 4; ++j) {
            long long gr = row0 + m_off + mi * 16 + cr + j;
            if (gr < N)
                #pragma unroll
                for (int ni = 0; ni < 2; ++ni)
                    HB[gr * OUTC + n_off + ni * 16 + cc] = f2bf(acc[mi][ni][j]);
        }
}

// ---- segment aggregation v3 ------------------------------------------------
// One wave per (node, 64-feature slice). Edge records loaded 64-at-a-time
// with ONE coalesced int2 load, then distributed via readlane (SGPR src/norm:
// scalar address math, no dependent broadcast loads). Gathers 16-deep.
template <int F, bool BIAS>
__global__ void seg_agg_v3(const ushort* __restrict__ HinB,
                           const float* __restrict__ dis,
                           const int* __restrict__ row_ptr,
                           const int2* __restrict__ epk,
                           const float* __restrict__ bias,
                           float* __restrict__ out, int N) {
    constexpr int SLICES = F / 64;  // 2 for F=128, 1 for F=64
    long long gw = ((long long)blockIdx.x * blockDim.x + threadIdx.x) >> 6;
    int lane = threadIdx.x & 63;
    int node = (SLICES == 2) ? (int)(gw >> 1) : (int)gw;
    int sl   = (SLICES == 2) ? ((int)gw & 1) : 0;
    if (node >= N) return;
    int f = sl * 64 + lane;
    float dn = dis[node];
    float acc = bf2f(HinB[(size_t)node * F + f]) * (dn * dn);  // self loop
    int e0 = row_ptr[node], e1 = row_ptr[node + 1];
    for (int base = e0; base < e1; base += 64) {
        int cnt = min(64, e1 - base);
        int2 rec = epk[min(base + lane, e1 - 1)];  // one coalesced 8B/lane load
        for (int u0 = 0; u0 < cnt; u0 += 16) {
            ushort hv[16];
            float nr[16];
            #pragma unroll
            for (int u = 0; u < 16; ++u) {
                int s = __builtin_amdgcn_readlane(rec.x, u0 + u);      // SGPR
                float nm = __int_as_float(__builtin_amdgcn_readlane(rec.y, u0 + u));
                nr[u] = (u0 + u < cnt) ? nm : 0.0f;                    // uniform
                hv[u] = HinB[(size_t)s * F + f];   // saddr + lane voffset
            }
            #pragma unroll
            for (int u = 0; u < 16; ++u)
                acc += bf2f(hv[u]) * nr[u];
        }
    }
    size_t ob = (size_t)node * F + f;
    out[ob] = BIAS ? acc + bias[f] : acc;
}

extern "C" void kernel_launch(void* const* d_in, const int* in_sizes, int n_in,
                              void* d_out, int out_size, void* d_ws, size_t ws_size,
                              hipStream_t stream) {
    const float* x  = (const float*)d_in[0];
    const void*  ei = d_in[1];
    const float* W1 = (const float*)d_in[2];
    const float* b1 = (const float*)d_in[3];
    const float* W2 = (const float*)d_in[4];
    const float* b2 = (const float*)d_in[5];
    float* out = (float*)d_out;
    int N = in_sizes[0] / IN_C;    // 50000
    int E = in_sizes[1] / 2;       // 800000

    char* ws = (char*)d_ws;
    size_t off = 0;
    auto alloc = [&](size_t bytes) {
        void* p = ws + off;
        off += ((bytes + 255) / 256) * 256;
        return p;
    };
    int nb = (N + SCAN_BLK - 1) / SCAN_BLK;  // 196
    int*    flag       = (int*)alloc(4);
    int*    degi       = (int*)alloc((size_t)N * 4);
    int*    bsum       = (int*)alloc((size_t)nb * 4);
    int*    row_ptr    = (int*)alloc(((size_t)N + 1) * 4);
    int*    cursor     = (int*)alloc((size_t)N * 4);
    float*  dis        = (float*)alloc((size_t)N * 4);
    int2*   epk        = (int2*)alloc((size_t)E * 8);
    ushort* w1h        = (ushort*)alloc((size_t)HID * IN_C * 2);
    ushort* w1l        = (ushort*)alloc((size_t)HID * IN_C * 2);
    ushort* w2h        = (ushort*)alloc((size_t)OUTC * HID * 2);
    ushort* w2l        = (ushort*)alloc((size_t)OUTC * HID * 2);
    ushort* H1b        = (ushort*)alloc((size_t)N * HID * 2);
    float*  AG1        = (float*)alloc((size_t)N * HID * 4);
    ushort* H2b        = (ushort*)alloc((size_t)N * OUTC * 2);

    hipMemsetAsync(degi, 0, (size_t)N * 4, stream);

    detect_kernel<<<1, 64, 0, stream>>>((const unsigned long long*)ei, flag);
    wtrans_kernel<<<(HID * IN_C + 255) / 256, 256, 0, stream>>>(W1, W2, w1h, w1l, w2h, w2l);
    degi_kernel<<<1024, 256, 0, stream>>>(ei, flag, degi, E);
    scan_sums_kernel<<<nb, SCAN_BLK, 0, stream>>>(degi, bsum, N);
    scan_bsum_kernel<<<1, SCAN_BLK, 0, stream>>>(bsum, nb);
    scan_emit_kernel<<<nb, SCAN_BLK, 0, stream>>>(degi, bsum, row_ptr, cursor, dis, N);
    scatter_kernel<<<1024, 256, 0, stream>>>(ei, flag, dis, cursor, epk, E);
    gemm1_mfma<<<(N + 63) / 64, 256, 0, stream>>>(x, w1h, w1l, H1b, N);
    seg_agg_v3<HID, false><<<(int)(((long long)N * 2 * 64 + 255) / 256), 256, 0, stream>>>(
        H1b, dis, row_ptr, epk, nullptr, AG1, N);
    gemm2_mfma<<<(N + 63) / 64, 256, 0, stream>>>(AG1, b1, w2h, w2l, H2b, N);
    seg_agg_v3<OUTC, true><<<(int)(((long long)N * 64 + 255) / 256), 256, 0, stream>>>(
        H2b, dis, row_ptr, epk, b2, out, N);
}

// Round 8
// 202.771 us; speedup vs baseline: 3.4695x; 1.0513x over previous
//
#include <hip/hip_runtime.h>

// GCN 2-layer encoder: N=50000 nodes, E=800000 edges, 256 -> 128 -> 64.
// Round 8: 4B packed edge records ((bf16norm15<<17)|src17) -> 1 readlane/edge,
// SALU unpack, SGPR-operand fmac; slice-major H1 [2][N][64] with per-slice
// launches for L2 temporal locality.

#define IN_C 256
#define HID 128
#define OUTC 64
#define SCAN_BLK 256

typedef __attribute__((ext_vector_type(8))) short short8;
typedef __attribute__((ext_vector_type(4))) float f32x4;

// ---- fp32 -> bf16 hi/lo split (exact to ~2^-17 rel) ------------------------
__device__ __forceinline__ void bf16split(float f, ushort& h, ushort& l) {
    unsigned u = __float_as_uint(f);
    h = (ushort)(u >> 16);
    float hf = __uint_as_float(u & 0xFFFF0000u);
    unsigned v = __float_as_uint(f - hf);
    l = (ushort)((v + 0x7FFF + ((v >> 16) & 1)) >> 16);
}

// fp32 -> bf16 round-to-nearest-even
__device__ __forceinline__ ushort f2bf(float f) {
    unsigned u = __float_as_uint(f);
    return (ushort)((u + 0x7FFF + ((u >> 16) & 1)) >> 16);
}
__device__ __forceinline__ float bf2f(ushort u) {
    return __uint_as_float((unsigned)u << 16);
}

// ---- swizzled LDS addressing for [row][64 k] bf16 tiles (128 B rows) -------
__device__ __forceinline__ void* lds_addr(void* base, int row, int kelem) {
    int byte = row * 128 + kelem * 2;
    byte ^= (row & 7) << 4;
    return (char*)base + byte;
}

// ---- edge index access (int64 vs int32 detected at runtime) ----------------
__device__ __forceinline__ int edge_at(const void* ei, long long idx, int is32) {
    return is32 ? ((const int*)ei)[idx] : (int)((const long long*)ei)[idx];
}

__global__ void detect_kernel(const unsigned long long* ei, int* flag) {
    if (threadIdx.x == 0 && blockIdx.x == 0) {
        int is32 = 0;
        for (int i = 0; i < 64; ++i)
            if (ei[i] >> 32) { is32 = 1; break; }
        *flag = is32;
    }
}

// ---- weight pre-transpose + split: W[k][n] -> WT_hi/lo[n][k] ---------------
__global__ void wtrans_kernel(const float* __restrict__ W1, const float* __restrict__ W2,
                              ushort* __restrict__ w1h, ushort* __restrict__ w1l,
                              ushort* __restrict__ w2h, ushort* __restrict__ w2l) {
    int id = blockIdx.x * blockDim.x + threadIdx.x;
    if (id < HID * IN_C) {                     // 128 n x 256 k
        int n = id >> 8, k = id & 255;
        ushort h, l; bf16split(W1[k * HID + n], h, l);
        w1h[id] = h; w1l[id] = l;
    }
    if (id < OUTC * HID) {                     // 64 n x 128 k
        int n = id >> 7, k = id & 127;
        ushort h, l; bf16split(W2[k * OUTC + n], h, l);
        w2h[id] = h; w2l[id] = l;
    }
}

// ---- integer degree histogram over dst -------------------------------------
__global__ void degi_kernel(const void* ei, const int* __restrict__ flag,
                            int* __restrict__ degi, int E) {
    int is32 = *flag;
    long long stride = (long long)gridDim.x * blockDim.x;
    for (long long e = (long long)blockIdx.x * blockDim.x + threadIdx.x; e < E; e += stride) {
        int d = edge_at(ei, (long long)E + e, is32);
        atomicAdd(&degi[d], 1);
    }
}

// ---- hierarchical exclusive scan -------------------------------------------
__global__ __launch_bounds__(SCAN_BLK) void scan_sums_kernel(const int* __restrict__ degi,
                                                             int* __restrict__ bsum, int N) {
    int i = blockIdx.x * SCAN_BLK + threadIdx.x;
    int v = (i < N) ? degi[i] : 0;
    #pragma unroll
    for (int d = 32; d > 0; d >>= 1) v += __shfl_down(v, d, 64);
    __shared__ int ws[4];
    if ((threadIdx.x & 63) == 0) ws[threadIdx.x >> 6] = v;
    __syncthreads();
    if (threadIdx.x == 0) bsum[blockIdx.x] = ws[0] + ws[1] + ws[2] + ws[3];
}

__global__ __launch_bounds__(SCAN_BLK) void scan_bsum_kernel(int* __restrict__ bsum, int nb) {
    __shared__ int sh[SCAN_BLK];
    int t = threadIdx.x;
    int v = (t < nb) ? bsum[t] : 0;
    sh[t] = v;
    __syncthreads();
    #pragma unroll
    for (int d = 1; d < SCAN_BLK; d <<= 1) {
        int add = (t >= d) ? sh[t - d] : 0;
        __syncthreads();
        sh[t] += add;
        __syncthreads();
    }
    if (t < nb) bsum[t] = sh[t] - v;  // exclusive
}

__global__ __launch_bounds__(SCAN_BLK) void scan_emit_kernel(const int* __restrict__ degi,
                                                             const int* __restrict__ bsum,
                                                             int* __restrict__ row_ptr,
                                                             int* __restrict__ cursor,
                                                             float* __restrict__ dis, int N) {
    __shared__ int sh[SCAN_BLK];
    int t = threadIdx.x;
    int i = blockIdx.x * SCAN_BLK + t;
    int v = (i < N) ? degi[i] : 0;
    sh[t] = v;
    __syncthreads();
    #pragma unroll
    for (int d = 1; d < SCAN_BLK; d <<= 1) {
        int add = (t >= d) ? sh[t - d] : 0;
        __syncthreads();
        sh[t] += add;
        __syncthreads();
    }
    if (i < N) {
        int excl = bsum[blockIdx.x] + sh[t] - v;
        row_ptr[i] = excl;
        cursor[i] = excl;
        dis[i] = rsqrtf((float)v + 1.0f);  // +1 = self loop
        if (i == N - 1) row_ptr[N] = excl + v;  // = E
    }
}

// ---- scatter packed records: (bf16norm[15b] << 17) | src[17b] --------------
__global__ void scatter_kernel(const void* ei, const int* __restrict__ flag,
                               const float* __restrict__ dis,
                               int* __restrict__ cursor, unsigned* __restrict__ epk,
                               int E) {
    int is32 = *flag;
    long long stride = (long long)gridDim.x * blockDim.x;
    for (long long e = (long long)blockIdx.x * blockDim.x + threadIdx.x; e < E; e += stride) {
        int s = edge_at(ei, e, is32);
        int d = edge_at(ei, (long long)E + e, is32);
        int pos = atomicAdd(&cursor[d], 1);
        unsigned u = __float_as_uint(dis[s] * dis[d]);
        unsigned bf15 = ((u + 0x7FFF + ((u >> 16) & 1)) >> 16) & 0x7FFF;
        epk[pos] = (bf15 << 17) | (unsigned)s;
    }
}

// ---- GEMM1 (MFMA): H[2][N][64] = X[N,256] @ W1  (bf16, slice-major) --------
__global__ __launch_bounds__(256) void gemm1_mfma(const float* __restrict__ X,
                                                  const ushort* __restrict__ WTh,
                                                  const ushort* __restrict__ WTl,
                                                  ushort* __restrict__ HB, int N) {
    __shared__ ushort XH[64 * 64], XL[64 * 64];     // 8 KB each
    __shared__ ushort WH[128 * 64], WL[128 * 64];   // 16 KB each
    int t = threadIdx.x;
    int lane = t & 63, w = t >> 6;
    int m_off = (w >> 1) * 32, n_off = (w & 1) * 64;
    long long row0 = (long long)blockIdx.x * 64;
    f32x4 acc[2][4] = {};
    for (int k0 = 0; k0 < IN_C; k0 += 64) {
        __syncthreads();
        {   // stage X tile: 64 rows x 64 k, fp32 -> hi/lo bf16
            int xr = t >> 4, xc = (t & 15) * 4;
            #pragma unroll
            for (int p = 0; p < 4; ++p) {
                int row = xr + p * 16;
                long long gr = row0 + row;
                float4 v = make_float4(0.f, 0.f, 0.f, 0.f);
                if (gr < N) v = *(const float4*)&X[gr * IN_C + k0 + xc];
                ushort4 h4, l4;
                bf16split(v.x, h4.x, l4.x); bf16split(v.y, h4.y, l4.y);
                bf16split(v.z, h4.z, l4.z); bf16split(v.w, h4.w, l4.w);
                *(ushort4*)lds_addr(XH, row, xc) = h4;
                *(ushort4*)lds_addr(XL, row, xc) = l4;
            }
        }
        {   // stage WT tiles: 128 n x 64 k per plane
            int wn = t >> 3, wk = (t & 7) * 8;
            #pragma unroll
            for (int p = 0; p < 4; ++p) {
                int n = wn + p * 32;
                *(short8*)lds_addr(WH, n, wk) = *(const short8*)&WTh[n * IN_C + k0 + wk];
                *(short8*)lds_addr(WL, n, wk) = *(const short8*)&WTl[n * IN_C + k0 + wk];
            }
        }
        __syncthreads();
        #pragma unroll
        for (int kk = 0; kk < 2; ++kk) {
            int ke = kk * 32 + (lane >> 4) * 8;
            short8 ah[2], al[2], bh[4], bl[4];
            #pragma unroll
            for (int mi = 0; mi < 2; ++mi) {
                int r = m_off + mi * 16 + (lane & 15);
                ah[mi] = *(short8*)lds_addr(XH, r, ke);
                al[mi] = *(short8*)lds_addr(XL, r, ke);
            }
            #pragma unroll
            for (int ni = 0; ni < 4; ++ni) {
                int r = n_off + ni * 16 + (lane & 15);
                bh[ni] = *(short8*)lds_addr(WH, r, ke);
                bl[ni] = *(short8*)lds_addr(WL, r, ke);
            }
            #pragma unroll
            for (int mi = 0; mi < 2; ++mi)
                #pragma unroll
                for (int ni = 0; ni < 4; ++ni) {
                    acc[mi][ni] = __builtin_amdgcn_mfma_f32_16x16x32_bf16(ah[mi], bh[ni], acc[mi][ni], 0, 0, 0);
                    acc[mi][ni] = __builtin_amdgcn_mfma_f32_16x16x32_bf16(ah[mi], bl[ni], acc[mi][ni], 0, 0, 0);
                    acc[mi][ni] = __builtin_amdgcn_mfma_f32_16x16x32_bf16(al[mi], bh[ni], acc[mi][ni], 0, 0, 0);
                }
        }
    }
    int cr = (lane >> 4) * 4, cc = lane & 15;
    #pragma unroll
    for (int mi = 0; mi < 2; ++mi)
        #pragma unroll
        for (int j = 0; j < 4; ++j) {
            long long gr = row0 + m_off + mi * 16 + cr + j;
            if (gr < N)
                #pragma unroll
                for (int ni = 0; ni < 4; ++ni) {
                    int col = n_off + ni * 16 + cc;
                    // slice-major: [col>>6][row][col&63]
                    HB[(size_t)(col >> 6) * N * 64 + gr * 64 + (col & 63)] =
                        f2bf(acc[mi][ni][j]);
                }
        }
}

// ---- GEMM2 (MFMA): H2[N,64] = relu(AG1[N,128]+b1) @ W2 (bf16 out) ----------
__global__ __launch_bounds__(256) void gemm2_mfma(const float* __restrict__ A,
                                                  const float* __restrict__ b1,
                                                  const ushort* __restrict__ WTh,
                                                  const ushort* __restrict__ WTl,
                                                  ushort* __restrict__ HB, int N) {
    __shared__ ushort AH[64 * 64], AL[64 * 64];
    __shared__ ushort WH[64 * 64], WL[64 * 64];
    int t = threadIdx.x;
    int lane = t & 63, w = t >> 6;
    int m_off = (w >> 1) * 32, n_off = (w & 1) * 32;
    long long row0 = (long long)blockIdx.x * 64;
    f32x4 acc[2][2] = {};
    for (int k0 = 0; k0 < HID; k0 += 64) {
        __syncthreads();
        {   // stage A tile with fused +b1, relu, hi/lo split
            int xr = t >> 4, xc = (t & 15) * 4;
            float4 bb = *(const float4*)&b1[k0 + xc];
            #pragma unroll
            for (int p = 0; p < 4; ++p) {
                int row = xr + p * 16;
                long long gr = row0 + row;
                float4 v = make_float4(0.f, 0.f, 0.f, 0.f);
                if (gr < N) {
                    v = *(const float4*)&A[gr * HID + k0 + xc];
                    v.x = fmaxf(v.x + bb.x, 0.f); v.y = fmaxf(v.y + bb.y, 0.f);
                    v.z = fmaxf(v.z + bb.z, 0.f); v.w = fmaxf(v.w + bb.w, 0.f);
                }
                ushort4 h4, l4;
                bf16split(v.x, h4.x, l4.x); bf16split(v.y, h4.y, l4.y);
                bf16split(v.z, h4.z, l4.z); bf16split(v.w, h4.w, l4.w);
                *(ushort4*)lds_addr(AH, row, xc) = h4;
                *(ushort4*)lds_addr(AL, row, xc) = l4;
            }
        }
        {   // stage W2T tiles: 64 n x 64 k per plane
            int wn = t >> 3, wk = (t & 7) * 8;
            #pragma unroll
            for (int p = 0; p < 2; ++p) {
                int n = wn + p * 32;
                *(short8*)lds_addr(WH, n, wk) = *(const short8*)&WTh[n * HID + k0 + wk];
                *(short8*)lds_addr(WL, n, wk) = *(const short8*)&WTl[n * HID + k0 + wk];
            }
        }
        __syncthreads();
        #pragma unroll
        for (int kk = 0; kk < 2; ++kk) {
            int ke = kk * 32 + (lane >> 4) * 8;
            short8 ah[2], al[2], bh[2], bl[2];
            #pragma unroll
            for (int mi = 0; mi < 2; ++mi) {
                int r = m_off + mi * 16 + (lane & 15);
                ah[mi] = *(short8*)lds_addr(AH, r, ke);
                al[mi] = *(short8*)lds_addr(AL, r, ke);
            }
            #pragma unroll
            for (int ni = 0; ni < 2; ++ni) {
                int r = n_off + ni * 16 + (lane & 15);
                bh[ni] = *(short8*)lds_addr(WH, r, ke);
                bl[ni] = *(short8*)lds_addr(WL, r, ke);
            }
            #pragma unroll
            for (int mi = 0; mi < 2; ++mi)
                #pragma unroll
                for (int ni = 0; ni < 2; ++ni) {
                    acc[mi][ni] = __builtin_amdgcn_mfma_f32_16x16x32_bf16(ah[mi], bh[ni], acc[mi][ni], 0, 0, 0);
                    acc[mi][ni] = __builtin_amdgcn_mfma_f32_16x16x32_bf16(ah[mi], bl[ni], acc[mi][ni], 0, 0, 0);
                    acc[mi][ni] = __builtin_amdgcn_mfma_f32_16x16x32_bf16(al[mi], bh[ni], acc[mi][ni], 0, 0, 0);
                }
        }
    }
    int cr = (lane >> 4) * 4, cc = lane & 15;
    #pragma unroll
    for (int mi = 0; mi < 2; ++mi)
        #pragma unroll
        for (int j = 0; j < 4; ++j) {
            long long gr = row0 + m_off + mi * 16 + cr + j;
            if (gr < N)
                #pragma unroll
                for (int ni = 0; ni < 2; ++ni)
                    HB[gr * OUTC + n_off + ni * 16 + cc] = f2bf(acc[mi][ni][j]);
        }
}

// ---- segment aggregation v4: one wave per node, one 64-feature slice -------
// 4B packed records: 1 readlane/edge; src*128B offset + norm stay scalar
// (SALU); 16 gathers in flight; fmac with SGPR norm operand.
__global__ __launch_bounds__(256) void seg_agg_v4(const ushort* __restrict__ Hsl,
                                                  const float* __restrict__ dis,
                                                  const int* __restrict__ row_ptr,
                                                  const unsigned* __restrict__ epk,
                                                  const float* __restrict__ bias,
                                                  float* __restrict__ out,
                                                  int N, int ostride) {
    int lane = threadIdx.x & 63;
    int node = (int)(((long long)blockIdx.x * blockDim.x + threadIdx.x) >> 6);
    if (node >= N) return;
    float dn = dis[node];
    const ushort* hl = Hsl + lane;
    float acc = bf2f(hl[node * 64]) * (dn * dn);   // self loop
    int e0 = row_ptr[node], e1 = row_ptr[node + 1];
    for (int base = e0; base < e1; base += 64) {
        int cnt = min(64, e1 - base);
        unsigned rec = epk[min(base + lane, e1 - 1)];  // one coalesced 4B/lane
        for (int u0 = 0; u0 < cnt; u0 += 16) {
            ushort hv[16]; float nr[16];
            #pragma unroll
            for (int u = 0; u < 16; ++u) {
                unsigned p = (unsigned)__builtin_amdgcn_readlane((int)rec, u0 + u);
                nr[u] = (u0 + u < cnt) ? __uint_as_float((p >> 1) & 0xFFFF0000u) : 0.0f;
                hv[u] = hl[(p & 0x1FFFF) * 64];
            }
            #pragma unroll
            for (int u = 0; u < 16; ++u)
                acc += bf2f(hv[u]) * nr[u];
        }
    }
    float r = bias ? acc + bias[lane] : acc;
    out[(size_t)node * ostride + lane] = r;
}

extern "C" void kernel_launch(void* const* d_in, const int* in_sizes, int n_in,
                              void* d_out, int out_size, void* d_ws, size_t ws_size,
                              hipStream_t stream) {
    const float* x  = (const float*)d_in[0];
    const void*  ei = d_in[1];
    const float* W1 = (const float*)d_in[2];
    const float* b1 = (const float*)d_in[3];
    const float* W2 = (const float*)d_in[4];
    const float* b2 = (const float*)d_in[5];
    float* out = (float*)d_out;
    int N = in_sizes[0] / IN_C;    // 50000
    int E = in_sizes[1] / 2;       // 800000

    char* ws = (char*)d_ws;
    size_t off = 0;
    auto alloc = [&](size_t bytes) {
        void* p = ws + off;
        off += ((bytes + 255) / 256) * 256;
        return p;
    };
    int nb = (N + SCAN_BLK - 1) / SCAN_BLK;  // 196
    int*      flag       = (int*)alloc(4);
    int*      degi       = (int*)alloc((size_t)N * 4);
    int*      bsum       = (int*)alloc((size_t)nb * 4);
    int*      row_ptr    = (int*)alloc(((size_t)N + 1) * 4);
    int*      cursor     = (int*)alloc((size_t)N * 4);
    float*    dis        = (float*)alloc((size_t)N * 4);
    unsigned* epk        = (unsigned*)alloc((size_t)E * 4);
    ushort*   w1h        = (ushort*)alloc((size_t)HID * IN_C * 2);
    ushort*   w1l        = (ushort*)alloc((size_t)HID * IN_C * 2);
    ushort*   w2h        = (ushort*)alloc((size_t)OUTC * HID * 2);
    ushort*   w2l        = (ushort*)alloc((size_t)OUTC * HID * 2);
    ushort*   H1b        = (ushort*)alloc((size_t)N * HID * 2);   // [2][N][64]
    float*    AG1        = (float*)alloc((size_t)N * HID * 4);
    ushort*   H2b        = (ushort*)alloc((size_t)N * OUTC * 2);

    hipMemsetAsync(degi, 0, (size_t)N * 4, stream);

    detect_kernel<<<1, 64, 0, stream>>>((const unsigned long long*)ei, flag);
    wtrans_kernel<<<(HID * IN_C + 255) / 256, 256, 0, stream>>>(W1, W2, w1h, w1l, w2h, w2l);
    degi_kernel<<<1024, 256, 0, stream>>>(ei, flag, degi, E);
    scan_sums_kernel<<<nb, SCAN_BLK, 0, stream>>>(degi, bsum, N);
    scan_bsum_kernel<<<1, SCAN_BLK, 0, stream>>>(bsum, nb);
    scan_emit_kernel<<<nb, SCAN_BLK, 0, stream>>>(degi, bsum, row_ptr, cursor, dis, N);
    scatter_kernel<<<1024, 256, 0, stream>>>(ei, flag, dis, cursor, epk, E);
    gemm1_mfma<<<(N + 63) / 64, 256, 0, stream>>>(x, w1h, w1l, H1b, N);

    int agg_blocks = (int)(((long long)N * 64 + 255) / 256);
    // layer-1 aggregation: one launch per 64-feature slice (L2 locality)
    seg_agg_v4<<<agg_blocks, 256, 0, stream>>>(H1b,            dis, row_ptr, epk,
                                               nullptr, AG1,      N, HID);
    seg_agg_v4<<<agg_blocks, 256, 0, stream>>>(H1b + (size_t)N * 64, dis, row_ptr, epk,
                                               nullptr, AG1 + 64, N, HID);
    gemm2_mfma<<<(N + 63) / 64, 256, 0, stream>>>(AG1, b1, w2h, w2l, H2b, N);
    seg_agg_v4<<<agg_blocks, 256, 0, stream>>>(H2b, dis, row_ptr, epk,
                                               b2, out, N, OUTC);
}

// Round 9
// 166.765 us; speedup vs baseline: 4.2185x; 1.2159x over previous
//
#include <hip/hip_runtime.h>

// GCN 2-layer encoder: N=50000 nodes, E=800000 edges, 256 -> 128 -> 64.
// Round 9: bucketed two-level counting sort (line-dense writes) replaces
// degi/scan/scatter; norm folded into pre-scaled hidden states Hs = H*dis
// so edge records are bare src indices; sentinel row for tail batches.

#define IN_C 256
#define HID 128
#define OUTC 64
#define NBLK 128   // blocks for bin_count/bin_scatter

typedef __attribute__((ext_vector_type(8))) short short8;
typedef __attribute__((ext_vector_type(4))) float f32x4;

// ---- fp32 -> bf16 hi/lo split (exact to ~2^-17 rel) ------------------------
__device__ __forceinline__ void bf16split(float f, ushort& h, ushort& l) {
    unsigned u = __float_as_uint(f);
    h = (ushort)(u >> 16);
    float hf = __uint_as_float(u & 0xFFFF0000u);
    unsigned v = __float_as_uint(f - hf);
    l = (ushort)((v + 0x7FFF + ((v >> 16) & 1)) >> 16);
}

__device__ __forceinline__ ushort f2bf(float f) {
    unsigned u = __float_as_uint(f);
    return (ushort)((u + 0x7FFF + ((u >> 16) & 1)) >> 16);
}
__device__ __forceinline__ float bf2f(ushort u) {
    return __uint_as_float((unsigned)u << 16);
}

// ---- swizzled LDS addressing for [row][64 k] bf16 tiles (128 B rows) -------
__device__ __forceinline__ void* lds_addr(void* base, int row, int kelem) {
    int byte = row * 128 + kelem * 2;
    byte ^= (row & 7) << 4;
    return (char*)base + byte;
}

// ---- edge index access (int64 vs int32 detected at runtime) ----------------
__device__ __forceinline__ int edge_at(const void* ei, long long idx, int is32) {
    return is32 ? ((const int*)ei)[idx] : (int)((const long long*)ei)[idx];
}

__global__ void detect_kernel(const unsigned long long* ei, int* flag) {
    if (threadIdx.x == 0 && blockIdx.x == 0) {
        int is32 = 0;
        for (int i = 0; i < 64; ++i)
            if (ei[i] >> 32) { is32 = 1; break; }
        *flag = is32;
    }
}

// ---- weight pre-transpose + split: W[k][n] -> WT_hi/lo[n][k] ---------------
__global__ void wtrans_kernel(const float* __restrict__ W1, const float* __restrict__ W2,
                              ushort* __restrict__ w1h, ushort* __restrict__ w1l,
                              ushort* __restrict__ w2h, ushort* __restrict__ w2l) {
    int id = blockIdx.x * blockDim.x + threadIdx.x;
    if (id < HID * IN_C) {                     // 128 n x 256 k
        int n = id >> 8, k = id & 255;
        ushort h, l; bf16split(W1[k * HID + n], h, l);
        w1h[id] = h; w1l[id] = l;
    }
    if (id < OUTC * HID) {                     // 64 n x 128 k
        int n = id >> 7, k = id & 127;
        ushort h, l; bf16split(W2[k * OUTC + n], h, l);
        w2h[id] = h; w2l[id] = l;
    }
}

// ---- pass 1: per-block histogram over dst buckets (dst>>8) -----------------
__global__ __launch_bounds__(256) void bin_count(const void* ei, const int* __restrict__ flag,
                                                 int* __restrict__ blkcnt, int E, int nb) {
    __shared__ int h[256];
    int t = threadIdx.x;
    h[t] = 0;
    __syncthreads();
    int is32 = *flag;
    int chunk = (E + gridDim.x - 1) / gridDim.x;
    long long s0 = (long long)blockIdx.x * chunk;
    long long s1 = s0 + chunk; if (s1 > E) s1 = E;
    for (long long e = s0 + t; e < s1; e += 256) {
        int d = edge_at(ei, (long long)E + e, is32);
        atomicAdd(&h[d >> 8], 1);
    }
    __syncthreads();
    if (t < nb) blkcnt[t * NBLK + blockIdx.x] = h[t];
}

// ---- pass 2: per-bucket prefix over blocks + bucket-base scan (1 block) ----
__global__ __launch_bounds__(256) void bin_scan(int* __restrict__ blkcnt,
                                                int* __restrict__ bbase, int nb) {
    __shared__ int sh[256];
    int t = threadIdx.x;
    int tot = 0;
    if (t < nb) {
        int4* p = (int4*)&blkcnt[t * NBLK];
        int run = 0;
        for (int i = 0; i < NBLK / 4; ++i) {
            int4 v = p[i]; int4 o;
            o.x = run; run += v.x; o.y = run; run += v.y;
            o.z = run; run += v.z; o.w = run; run += v.w;
            p[i] = o;
        }
        tot = run;
    }
    sh[t] = tot;
    __syncthreads();
    for (int d = 1; d < 256; d <<= 1) {
        int add = (t >= d) ? sh[t - d] : 0;
        __syncthreads();
        sh[t] += add;
        __syncthreads();
    }
    if (t < nb) {
        bbase[t] = sh[t] - tot;              // exclusive
        if (t == nb - 1) bbase[nb] = sh[t];  // = E
    }
}

// ---- pass 3: scatter records into per-(block,bucket) contiguous segments ---
// record = src[17b] | dstlow8 << 17
__global__ __launch_bounds__(256) void bin_scatter(const void* ei, const int* __restrict__ flag,
                                                   const int* __restrict__ blkcnt,
                                                   const int* __restrict__ bbase,
                                                   unsigned* __restrict__ coarse, int E, int nb) {
    __shared__ int cur[256];
    int t = threadIdx.x;
    if (t < nb) cur[t] = bbase[t] + blkcnt[t * NBLK + blockIdx.x];
    __syncthreads();
    int is32 = *flag;
    int chunk = (E + gridDim.x - 1) / gridDim.x;
    long long s0 = (long long)blockIdx.x * chunk;
    long long s1 = s0 + chunk; if (s1 > E) s1 = E;
    for (long long e = s0 + t; e < s1; e += 256) {
        int s = edge_at(ei, e, is32);
        int d = edge_at(ei, (long long)E + e, is32);
        int p = atomicAdd(&cur[d >> 8], 1);
        coarse[p] = (unsigned)s | ((unsigned)(d & 255) << 17);
    }
}

// ---- pass 4: per-bucket exact sort by dst; emits row_ptr, dis, epk ---------
__global__ __launch_bounds__(256) void fine_kernel(const unsigned* __restrict__ coarse,
                                                   const int* __restrict__ bbase,
                                                   int* __restrict__ row_ptr,
                                                   float* __restrict__ dis,
                                                   int* __restrict__ epk, int N, int nb) {
    __shared__ int h[256], cur[256], sh[256];
    int b = blockIdx.x, t = threadIdx.x;
    int nb0 = b << 8;
    int e0b = bbase[b], e1b = bbase[b + 1];
    h[t] = 0;
    __syncthreads();
    for (int e = e0b + t; e < e1b; e += 256)
        atomicAdd(&h[(coarse[e] >> 17) & 0xFF], 1);
    __syncthreads();
    int cnt = h[t];
    sh[t] = cnt;
    __syncthreads();
    for (int d = 1; d < 256; d <<= 1) {
        int add = (t >= d) ? sh[t - d] : 0;
        __syncthreads();
        sh[t] += add;
        __syncthreads();
    }
    int excl = sh[t] - cnt;
    int node = nb0 + t;
    if (node < N) {
        row_ptr[node] = e0b + excl;
        dis[node] = rsqrtf((float)cnt + 1.0f);   // +1 = self loop
        if (node == N - 1) row_ptr[N] = e0b + sh[t];  // = E
    }
    cur[t] = e0b + excl;
    __syncthreads();
    for (int e = e0b + t; e < e1b; e += 256) {
        unsigned r = coarse[e];
        int p = atomicAdd(&cur[(r >> 17) & 0xFF], 1);
        epk[p] = (int)(r & 0x1FFFF);
    }
}

// ---- zero the sentinel rows (row N of each pre-scaled H buffer) ------------
__global__ void zsent_kernel(ushort* a, ushort* b, ushort* c) {
    int t = threadIdx.x;
    if (t < 64) { a[t] = 0; b[t] = 0; c[t] = 0; }
}

// ---- GEMM1 (MFMA): Hs[2][N+1][64] = (X @ W1) * dis[row]  (bf16) ------------
__global__ __launch_bounds__(256) void gemm1_mfma(const float* __restrict__ X,
                                                  const ushort* __restrict__ WTh,
                                                  const ushort* __restrict__ WTl,
                                                  const float* __restrict__ dis,
                                                  ushort* __restrict__ HB, int N) {
    __shared__ ushort XH[64 * 64], XL[64 * 64];     // 8 KB each
    __shared__ ushort WH[128 * 64], WL[128 * 64];   // 16 KB each
    int t = threadIdx.x;
    int lane = t & 63, w = t >> 6;
    int m_off = (w >> 1) * 32, n_off = (w & 1) * 64;
    long long row0 = (long long)blockIdx.x * 64;
    size_t sstride = (size_t)(N + 1) * 64;
    f32x4 acc[2][4] = {};
    for (int k0 = 0; k0 < IN_C; k0 += 64) {
        __syncthreads();
        {   // stage X tile: 64 rows x 64 k, fp32 -> hi/lo bf16
            int xr = t >> 4, xc = (t & 15) * 4;
            #pragma unroll
            for (int p = 0; p < 4; ++p) {
                int row = xr + p * 16;
                long long gr = row0 + row;
                float4 v = make_float4(0.f, 0.f, 0.f, 0.f);
                if (gr < N) v = *(const float4*)&X[gr * IN_C + k0 + xc];
                ushort4 h4, l4;
                bf16split(v.x, h4.x, l4.x); bf16split(v.y, h4.y, l4.y);
                bf16split(v.z, h4.z, l4.z); bf16split(v.w, h4.w, l4.w);
                *(ushort4*)lds_addr(XH, row, xc) = h4;
                *(ushort4*)lds_addr(XL, row, xc) = l4;
            }
        }
        {   // stage WT tiles: 128 n x 64 k per plane
            int wn = t >> 3, wk = (t & 7) * 8;
            #pragma unroll
            for (int p = 0; p < 4; ++p) {
                int n = wn + p * 32;
                *(short8*)lds_addr(WH, n, wk) = *(const short8*)&WTh[n * IN_C + k0 + wk];
                *(short8*)lds_addr(WL, n, wk) = *(const short8*)&WTl[n * IN_C + k0 + wk];
            }
        }
        __syncthreads();
        #pragma unroll
        for (int kk = 0; kk < 2; ++kk) {
            int ke = kk * 32 + (lane >> 4) * 8;
            short8 ah[2], al[2], bh[4], bl[4];
            #pragma unroll
            for (int mi = 0; mi < 2; ++mi) {
                int r = m_off + mi * 16 + (lane & 15);
                ah[mi] = *(short8*)lds_addr(XH, r, ke);
                al[mi] = *(short8*)lds_addr(XL, r, ke);
            }
            #pragma unroll
            for (int ni = 0; ni < 4; ++ni) {
                int r = n_off + ni * 16 + (lane & 15);
                bh[ni] = *(short8*)lds_addr(WH, r, ke);
                bl[ni] = *(short8*)lds_addr(WL, r, ke);
            }
            #pragma unroll
            for (int mi = 0; mi < 2; ++mi)
                #pragma unroll
                for (int ni = 0; ni < 4; ++ni) {
                    acc[mi][ni] = __builtin_amdgcn_mfma_f32_16x16x32_bf16(ah[mi], bh[ni], acc[mi][ni], 0, 0, 0);
                    acc[mi][ni] = __builtin_amdgcn_mfma_f32_16x16x32_bf16(ah[mi], bl[ni], acc[mi][ni], 0, 0, 0);
                    acc[mi][ni] = __builtin_amdgcn_mfma_f32_16x16x32_bf16(al[mi], bh[ni], acc[mi][ni], 0, 0, 0);
                }
        }
    }
    int cr = (lane >> 4) * 4, cc = lane & 15;
    #pragma unroll
    for (int mi = 0; mi < 2; ++mi)
        #pragma unroll
        for (int j = 0; j < 4; ++j) {
            long long gr = row0 + m_off + mi * 16 + cr + j;
            if (gr < N) {
                float dv = dis[gr];
                #pragma unroll
                for (int ni = 0; ni < 4; ++ni) {
                    int col = n_off + ni * 16 + cc;
                    HB[(size_t)(col >> 6) * sstride + gr * 64 + (col & 63)] =
                        f2bf(acc[mi][ni][j] * dv);
                }
            }
        }
}

// ---- GEMM2 (MFMA): Hs2[N+1][64] = relu(AG1+b1) @ W2 * dis[row] (bf16) ------
__global__ __launch_bounds__(256) void gemm2_mfma(const float* __restrict__ A,
                                                  const float* __restrict__ b1,
                                                  const ushort* __restrict__ WTh,
                                                  const ushort* __restrict__ WTl,
                                                  const float* __restrict__ dis,
                                                  ushort* __restrict__ HB, int N) {
    __shared__ ushort AH[64 * 64], AL[64 * 64];
    __shared__ ushort WH[64 * 64], WL[64 * 64];
    int t = threadIdx.x;
    int lane = t & 63, w = t >> 6;
    int m_off = (w >> 1) * 32, n_off = (w & 1) * 32;
    long long row0 = (long long)blockIdx.x * 64;
    f32x4 acc[2][2] = {};
    for (int k0 = 0; k0 < HID; k0 += 64) {
        __syncthreads();
        {   // stage A tile with fused +b1, relu, hi/lo split
            int xr = t >> 4, xc = (t & 15) * 4;
            float4 bb = *(const float4*)&b1[k0 + xc];
            #pragma unroll
            for (int p = 0; p < 4; ++p) {
                int row = xr + p * 16;
                long long gr = row0 + row;
                float4 v = make_float4(0.f, 0.f, 0.f, 0.f);
                if (gr < N) {
                    v = *(const float4*)&A[gr * HID + k0 + xc];
                    v.x = fmaxf(v.x + bb.x, 0.f); v.y = fmaxf(v.y + bb.y, 0.f);
                    v.z = fmaxf(v.z + bb.z, 0.f); v.w = fmaxf(v.w + bb.w, 0.f);
                }
                ushort4 h4, l4;
                bf16split(v.x, h4.x, l4.x); bf16split(v.y, h4.y, l4.y);
                bf16split(v.z, h4.z, l4.z); bf16split(v.w, h4.w, l4.w);
                *(ushort4*)lds_addr(AH, row, xc) = h4;
                *(ushort4*)lds_addr(AL, row, xc) = l4;
            }
        }
        {   // stage W2T tiles: 64 n x 64 k per plane
            int wn = t >> 3, wk = (t & 7) * 8;
            #pragma unroll
            for (int p = 0; p < 2; ++p) {
                int n = wn + p * 32;
                *(short8*)lds_addr(WH, n, wk) = *(const short8*)&WTh[n * HID + k0 + wk];
                *(short8*)lds_addr(WL, n, wk) = *(const short8*)&WTl[n * HID + k0 + wk];
            }
        }
        __syncthreads();
        #pragma unroll
        for (int kk = 0; kk < 2; ++kk) {
            int ke = kk * 32 + (lane >> 4) * 8;
            short8 ah[2], al[2], bh[2], bl[2];
            #pragma unroll
            for (int mi = 0; mi < 2; ++mi) {
                int r = m_off + mi * 16 + (lane & 15);
                ah[mi] = *(short8*)lds_addr(AH, r, ke);
                al[mi] = *(short8*)lds_addr(AL, r, ke);
            }
            #pragma unroll
            for (int ni = 0; ni < 2; ++ni) {
                int r = n_off + ni * 16 + (lane & 15);
                bh[ni] = *(short8*)lds_addr(WH, r, ke);
                bl[ni] = *(short8*)lds_addr(WL, r, ke);
            }
            #pragma unroll
            for (int mi = 0; mi < 2; ++mi)
                #pragma unroll
                for (int ni = 0; ni < 2; ++ni) {
                    acc[mi][ni] = __builtin_amdgcn_mfma_f32_16x16x32_bf16(ah[mi], bh[ni], acc[mi][ni], 0, 0, 0);
                    acc[mi][ni] = __builtin_amdgcn_mfma_f32_16x16x32_bf16(ah[mi], bl[ni], acc[mi][ni], 0, 0, 0);
                    acc[mi][ni] = __builtin_amdgcn_mfma_f32_16x16x32_bf16(al[mi], bh[ni], acc[mi][ni], 0, 0, 0);
                }
        }
    }
    int cr = (lane >> 4) * 4, cc = lane & 15;
    #pragma unroll
    for (int mi = 0; mi < 2; ++mi)
        #pragma unroll
        for (int j = 0; j < 4; ++j) {
            long long gr = row0 + m_off + mi * 16 + cr + j;
            if (gr < N) {
                float dv = dis[gr];
                #pragma unroll
                for (int ni = 0; ni < 2; ++ni)
                    HB[gr * OUTC + n_off + ni * 16 + cc] = f2bf(acc[mi][ni][j] * dv);
            }
        }
}

// ---- segment aggregation v5: pre-scaled rows, bare src records -------------
// out[n] = dis[n] * ( sum_e Hs[src_e] + Hs[n] ) (+ bias). Sentinel row N = 0.
__global__ __launch_bounds__(256) void seg_agg_v5(const ushort* __restrict__ Hsl,
                                                  const float* __restrict__ dis,
                                                  const int* __restrict__ row_ptr,
                                                  const int* __restrict__ epk,
                                                  const float* __restrict__ bias,
                                                  float* __restrict__ out,
                                                  int N, int ostride) {
    int lane = threadIdx.x & 63;
    int node = (int)(((long long)blockIdx.x * blockDim.x + threadIdx.x) >> 6);
    if (node >= N) return;
    const ushort* hl = Hsl + lane;
    float acc = bf2f(hl[node * 64]);   // self loop (pre-scaled)
    int e0 = row_ptr[node], e1 = row_ptr[node + 1];
    for (int base = e0; base < e1; base += 64) {
        int cnt = min(64, e1 - base);
        int rec = epk[min(base + lane, e1 - 1)];  // one coalesced 4B/lane load
        for (int u0 = 0; u0 < cnt; u0 += 16) {
            float hv[16];
            #pragma unroll
            for (int u = 0; u < 16; ++u) {
                int s = (u0 + u < cnt) ? __builtin_amdgcn_readlane(rec, u0 + u) : N;
                hv[u] = bf2f(hl[s * 64]);
            }
            #pragma unroll
            for (int u = 0; u < 16; ++u)
                acc += hv[u];
        }
    }
    float r = dis[node] * acc;
    if (bias) r += bias[lane];
    out[(size_t)node * ostride + lane] = r;
}

extern "C" void kernel_launch(void* const* d_in, const int* in_sizes, int n_in,
                              void* d_out, int out_size, void* d_ws, size_t ws_size,
                              hipStream_t stream) {
    const float* x  = (const float*)d_in[0];
    const void*  ei = d_in[1];
    const float* W1 = (const float*)d_in[2];
    const float* b1 = (const float*)d_in[3];
    const float* W2 = (const float*)d_in[4];
    const float* b2 = (const float*)d_in[5];
    float* out = (float*)d_out;
    int N = in_sizes[0] / IN_C;    // 50000
    int E = in_sizes[1] / 2;       // 800000
    int nb = (N + 255) >> 8;       // 196 dst buckets (assumes nb <= 256)

    char* ws = (char*)d_ws;
    size_t off = 0;
    auto alloc = [&](size_t bytes) {
        void* p = ws + off;
        off += ((bytes + 255) / 256) * 256;
        return p;
    };
    int*      flag    = (int*)alloc(4);
    int*      blkcnt  = (int*)alloc((size_t)nb * NBLK * 4);
    int*      bbase   = (int*)alloc(((size_t)nb + 1) * 4);
    int*      row_ptr = (int*)alloc(((size_t)N + 1) * 4);
    float*    dis     = (float*)alloc((size_t)N * 4);
    unsigned* coarse  = (unsigned*)alloc((size_t)E * 4);
    int*      epk     = (int*)alloc((size_t)E * 4);
    ushort*   w1h     = (ushort*)alloc((size_t)HID * IN_C * 2);
    ushort*   w1l     = (ushort*)alloc((size_t)HID * IN_C * 2);
    ushort*   w2h     = (ushort*)alloc((size_t)OUTC * HID * 2);
    ushort*   w2l     = (ushort*)alloc((size_t)OUTC * HID * 2);
    size_t sstride    = (size_t)(N + 1) * 64;
    ushort*   H1b     = (ushort*)alloc(2 * sstride * 2);   // [2][N+1][64] bf16
    float*    AG1     = (float*)alloc((size_t)N * HID * 4);
    ushort*   H2b     = (ushort*)alloc(sstride * 2);       // [N+1][64] bf16

    detect_kernel<<<1, 64, 0, stream>>>((const unsigned long long*)ei, flag);
    wtrans_kernel<<<(HID * IN_C + 255) / 256, 256, 0, stream>>>(W1, W2, w1h, w1l, w2h, w2l);
    bin_count<<<NBLK, 256, 0, stream>>>(ei, flag, blkcnt, E, nb);
    bin_scan<<<1, 256, 0, stream>>>(blkcnt, bbase, nb);
    bin_scatter<<<NBLK, 256, 0, stream>>>(ei, flag, blkcnt, bbase, coarse, E, nb);
    fine_kernel<<<nb, 256, 0, stream>>>(coarse, bbase, row_ptr, dis, epk, N, nb);
    zsent_kernel<<<1, 64, 0, stream>>>(H1b + (size_t)N * 64,
                                       H1b + sstride + (size_t)N * 64,
                                       H2b + (size_t)N * 64);
    gemm1_mfma<<<(N + 63) / 64, 256, 0, stream>>>(x, w1h, w1l, dis, H1b, N);

    int agg_blocks = (int)(((long long)N * 64 + 255) / 256);
    seg_agg_v5<<<agg_blocks, 256, 0, stream>>>(H1b,           dis, row_ptr, epk,
                                               nullptr, AG1,      N, HID);
    seg_agg_v5<<<agg_blocks, 256, 0, stream>>>(H1b + sstride, dis, row_ptr, epk,
                                               nullptr, AG1 + 64, N, HID);
    gemm2_mfma<<<(N + 63) / 64, 256, 0, stream>>>(AG1, b1, w2h, w2l, dis, H2b, N);
    seg_agg_v5<<<agg_blocks, 256, 0, stream>>>(H2b, dis, row_ptr, epk,
                                               b2, out, N, OUTC);
}